// Round 1
// baseline (913.781 us; speedup 1.0000x reference)
//
#include <hip/hip_runtime.h>

// ---------------- helpers ----------------
static __device__ __forceinline__ float reflectf(float coord, float m) {
    // m = size-1 (>0 here). period = 2m fold, then clamp to [0,m].
    float period = 2.0f * m;
    float c = fmodf(fabsf(coord), period);
    c = (c > m) ? (period - c) : c;
    return fminf(fmaxf(c, 0.0f), m);
}

// ---------------- k_prep: average the 6-channel offset conv into 2 maps ----------------
__global__ __launch_bounds__(256) void k_prep(
    const float* __restrict__ offw0, const float* __restrict__ offb0,
    const float* __restrict__ offw1, const float* __restrict__ offb1,
    float* __restrict__ avgw, float* __restrict__ avgb) {
    int id = blockIdx.x * blockDim.x + threadIdx.x;
    if (id < 2 * 2 * 2304) {
        int l = id / 4608;
        int rem = id % 4608;
        int d = rem / 2304;   // 0 = x-dir (out ch 0..2), 1 = y-dir (out ch 3..5)
        int r = rem % 2304;   // ci*9 + tap
        const float* w = l ? offw1 : offw0;
        float s = w[(d * 3 + 0) * 2304 + r] + w[(d * 3 + 1) * 2304 + r] + w[(d * 3 + 2) * 2304 + r];
        avgw[id] = s * (1.0f / 3.0f);
    }
    if (id == 0) {
        avgb[0] = (offb0[0] + offb0[1] + offb0[2]) * (1.0f / 3.0f);
        avgb[1] = (offb0[3] + offb0[4] + offb0[5]) * (1.0f / 3.0f);
        avgb[2] = (offb1[0] + offb1[1] + offb1[2]) * (1.0f / 3.0f);
        avgb[3] = (offb1[3] + offb1[4] + offb1[5]) * (1.0f / 3.0f);
    }
}

// ---------------- k_wt: Haar DWT, input strided (so level-1 reads tag0 LL directly) ----------------
__global__ __launch_bounds__(256) void k_wt(
    const float* __restrict__ in, float* __restrict__ tag,
    int B, int C, int H, int W, long sB, long sC) {
    int hh = H >> 1, ww = W >> 1;
    int total = B * C * hh * ww;
    int id = blockIdx.x * blockDim.x + threadIdx.x;
    if (id >= total) return;
    int j = id % ww; int t = id / ww;
    int i = t % hh; t /= hh;
    int c = t % C; int b = t / C;
    const float* p = in + (long)b * sB + (long)c * sC + (long)(2 * i) * W + 2 * j;
    float a0 = p[0], a1 = p[1], a2 = p[W], a3 = p[W + 1];
    float k0 = 0.5f * (a0 + a1 + a2 + a3);   // LL  (lo x lo)
    float k1 = 0.5f * (a0 + a1 - a2 - a3);   // hi rows
    float k2 = 0.5f * (a0 - a1 + a2 - a3);   // hi cols
    float k3 = 0.5f * (a0 - a1 - a2 + a3);   // hi hi
    long os = (long)hh * ww;
    float* o = tag + ((long)b * C * 4 + (long)c * 4) * os + (long)i * ww + j;
    o[0] = k0; o[os] = k1; o[2 * os] = k2; o[3 * os] = k3;
}

// ---------------- k_off: 256->2 3x3 conv (averaged weights), zero pad ----------------
__global__ __launch_bounds__(256) void k_off(
    const float* __restrict__ tag, const float* __restrict__ avgw,
    const float* __restrict__ avgb, int level,
    float* __restrict__ ox, float* __restrict__ oy,
    int B, int hh, int ww) {
    __shared__ float w[4608];
    const float* wsrc = avgw + level * 4608;
    for (int t = threadIdx.x; t < 4608; t += blockDim.x) w[t] = wsrc[t];
    __syncthreads();
    float bx = avgb[level * 2 + 0], by = avgb[level * 2 + 1];
    int id = blockIdx.x * blockDim.x + threadIdx.x;
    int npix = hh * ww;
    if (id >= B * npix) return;
    int j = id % ww; int t = id / ww;
    int i = t % hh; int b = t / hh;
    float ax = bx, ay = by;
    const float* base = tag + (long)b * 256 * npix;
    for (int ci = 0; ci < 256; ci++) {
        const float* pc = base + (long)ci * npix;
        const float* wx = w + ci * 9;
        const float* wy = w + 2304 + ci * 9;
        #pragma unroll
        for (int di = 0; di < 3; di++) {
            int y = i + di - 1;
            if ((unsigned)y >= (unsigned)hh) continue;
            #pragma unroll
            for (int dj = 0; dj < 3; dj++) {
                int x = j + dj - 1;
                if ((unsigned)x >= (unsigned)ww) continue;
                float v = pc[y * ww + x];
                ax = fmaf(v, wx[di * 3 + dj], ax);
                ay = fmaf(v, wy[di * 3 + dj], ay);
            }
        }
    }
    ox[id] = ax; oy[id] = ay;
}

// ---------------- k_snake: grid-sample (reflect) -> LDS tile -> dw3x3+ReLU -> grouped 1x1 -> scale ----------------
__global__ __launch_bounds__(256) void k_snake(
    const float* __restrict__ tag,
    const float* __restrict__ ox, const float* __restrict__ oy,
    const float* __restrict__ dww, const float* __restrict__ pww,
    const float* __restrict__ wsc,
    float* __restrict__ out, int B, int hh, int ww) {
    __shared__ float s[4][18][18];
    __shared__ float dwW[36];
    __shared__ float pwW[16];
    __shared__ float wscW[4];
    int tilesX = ww >> 4;
    int tile = blockIdx.x;
    int g = blockIdx.y;   // channel group 0..63
    int b = blockIdx.z;
    int i0 = (tile / tilesX) * 16;
    int j0 = (tile % tilesX) * 16;
    int tid = threadIdx.x;
    if (tid < 36) dwW[tid] = dww[g * 36 + tid];
    else if (tid < 52) pwW[tid - 36] = pww[g * 16 + (tid - 36)];
    else if (tid < 56) wscW[tid - 52] = wsc[g * 4 + (tid - 52)];
    int npix = hh * ww;
    const float* tb = tag + ((long)b * 256 + (long)g * 4) * npix;
    const float* oxb = ox + (long)b * npix;
    const float* oyb = oy + (long)b * npix;
    float mW = (float)(ww - 1), mH = (float)(hh - 1);
    for (int p = tid; p < 324; p += 256) {
        int ty = p / 18, tx = p % 18;
        int y = i0 - 1 + ty, x = j0 - 1 + tx;
        float v0 = 0.f, v1 = 0.f, v2 = 0.f, v3 = 0.f;
        if ((unsigned)y < (unsigned)hh && (unsigned)x < (unsigned)ww) {
            float px = (float)x + oxb[y * ww + x];
            float py = (float)y + oyb[y * ww + x];
            px = reflectf(px, mW);
            py = reflectf(py, mH);
            float x0f = floorf(px), y0f = floorf(py);
            float fx = px - x0f, fy = py - y0f;
            int x0 = min(max((int)x0f, 0), ww - 1);
            int y0 = min(max((int)y0f, 0), hh - 1);
            int x1 = min(x0 + 1, ww - 1);
            int y1 = min(y0 + 1, hh - 1);
            float w00 = (1.f - fx) * (1.f - fy), w01 = fx * (1.f - fy);
            float w10 = (1.f - fx) * fy,         w11 = fx * fy;
            int i00 = y0 * ww + x0, i01 = y0 * ww + x1;
            int i10 = y1 * ww + x0, i11 = y1 * ww + x1;
            const float* c0 = tb;
            const float* c1 = tb + npix;
            const float* c2 = tb + 2 * (long)npix;
            const float* c3 = tb + 3 * (long)npix;
            v0 = c0[i00] * w00 + c0[i01] * w01 + c0[i10] * w10 + c0[i11] * w11;
            v1 = c1[i00] * w00 + c1[i01] * w01 + c1[i10] * w10 + c1[i11] * w11;
            v2 = c2[i00] * w00 + c2[i01] * w01 + c2[i10] * w10 + c2[i11] * w11;
            v3 = c3[i00] * w00 + c3[i01] * w01 + c3[i10] * w10 + c3[i11] * w11;
        }
        s[0][ty][tx] = v0;
        s[1][ty][tx] = v1;
        s[2][ty][tx] = v2;
        s[3][ty][tx] = v3;
    }
    __syncthreads();
    int ti = tid >> 4, tj = tid & 15;
    int i = i0 + ti, j = j0 + tj;
    float r[4];
    #pragma unroll
    for (int cc = 0; cc < 4; cc++) {
        float acc = 0.f;
        #pragma unroll
        for (int di = 0; di < 3; di++)
            #pragma unroll
            for (int dj = 0; dj < 3; dj++)
                acc = fmaf(s[cc][ti + di][tj + dj], dwW[cc * 9 + di * 3 + dj], acc);
        r[cc] = fmaxf(acc, 0.f);
    }
    #pragma unroll
    for (int oo = 0; oo < 4; oo++) {
        float o = r[0] * pwW[oo * 4 + 0] + r[1] * pwW[oo * 4 + 1]
                + r[2] * pwW[oo * 4 + 2] + r[3] * pwW[oo * 4 + 3];
        out[(((long)b * 256 + (long)g * 4 + oo) * npix) + (long)i * ww + j] = o * wscW[oo];
    }
}

// ---------------- k_iwt: inverse Haar (level 1) ----------------
__global__ __launch_bounds__(256) void k_iwt(
    const float* __restrict__ coef, float* __restrict__ out,
    int B, int C, int hh, int ww) {
    int total = B * C * hh * ww;
    int id = blockIdx.x * blockDim.x + threadIdx.x;
    if (id >= total) return;
    int j = id % ww; int t = id / ww;
    int i = t % hh; t /= hh;
    int c = t % C; int b = t / C;
    long npix = (long)hh * ww;
    const float* p = coef + ((long)b * C * 4 + (long)c * 4) * npix + (long)i * ww + j;
    float c0 = p[0], c1 = p[npix], c2 = p[2 * npix], c3 = p[3 * npix];
    int W2 = ww * 2;
    float* o = out + (((long)b * C + c) * (2 * (long)hh) + 2 * i) * W2 + 2 * j;
    o[0]      = 0.5f * (c0 + c1 + c2 + c3);
    o[1]      = 0.5f * (c0 + c1 - c2 - c3);
    o[W2]     = 0.5f * (c0 - c1 + c2 - c3);
    o[W2 + 1] = 0.5f * (c0 - c1 - c2 + c3);
}

// ---------------- k_final: level-0 inverse Haar (+nxt1 into LL) + base depthwise conv + add ----------------
__global__ __launch_bounds__(256) void k_final(
    const float* __restrict__ tagp0, const float* __restrict__ nxt1,
    const float* __restrict__ x,
    const float* __restrict__ bw, const float* __restrict__ bb,
    const float* __restrict__ bs, float* __restrict__ out) {
    const int W = 128, H = 128, C = 64, hh = 64, ww = 64;
    int id = blockIdx.x * blockDim.x + threadIdx.x;
    if (id >= 16 * C * H * W) return;
    int xx = id % W; int t = id / W;
    int yy = t % H; t /= H;
    int c = t % C; int b = t / C;
    int i = yy >> 1, j = xx >> 1, dy = yy & 1, dx = xx & 1;
    long npix = (long)hh * ww;
    const float* p = tagp0 + ((long)b * 256 + (long)c * 4) * npix + (long)i * ww + j;
    float c0 = p[0] + nxt1[(((long)b * C + c) * hh + i) * ww + j];
    float c1 = p[npix], c2 = p[2 * npix], c3 = p[3 * npix];
    float s1 = dy ? -1.f : 1.f;
    float s2 = dx ? -1.f : 1.f;
    float rec = 0.5f * (c0 + s1 * c1 + s2 * c2 + s1 * s2 * c3);
    float acc = bb[c];
    const float* xb = x + ((long)b * C + c) * (long)(H * W);
    const float* wb = bw + c * 9;
    #pragma unroll
    for (int di = 0; di < 3; di++) {
        int y2 = yy + di - 1;
        if ((unsigned)y2 >= (unsigned)H) continue;
        #pragma unroll
        for (int dj = 0; dj < 3; dj++) {
            int x2 = xx + dj - 1;
            if ((unsigned)x2 >= (unsigned)W) continue;
            acc = fmaf(xb[y2 * W + x2], wb[di * 3 + dj], acc);
        }
    }
    out[id] = bs[c] * acc + rec;
}

// ---------------- launch ----------------
extern "C" void kernel_launch(void* const* d_in, const int* in_sizes, int n_in,
                              void* d_out, int out_size, void* d_ws, size_t ws_size,
                              hipStream_t stream) {
    const float* x     = (const float*)d_in[0];
    const float* bw    = (const float*)d_in[1];
    const float* bb    = (const float*)d_in[2];
    const float* bs    = (const float*)d_in[3];
    const float* offw0 = (const float*)d_in[4];
    const float* offb0 = (const float*)d_in[5];
    const float* dww0  = (const float*)d_in[6];
    const float* pww0  = (const float*)d_in[7];
    const float* wsc0  = (const float*)d_in[8];
    const float* offw1 = (const float*)d_in[9];
    const float* offb1 = (const float*)d_in[10];
    const float* dww1  = (const float*)d_in[11];
    const float* pww1  = (const float*)d_in[12];
    const float* wsc1  = (const float*)d_in[13];
    float* out = (float*)d_out;
    float* ws = (float*)d_ws;

    // float-offset workspace layout (~160.7 MiB total)
    float* tag0  = ws + 0L;              // 16,777,216
    float* tag1  = ws + 16777216L;       //  4,194,304  (reused as nxt1 after tagp1 is built)
    float* tagp1 = ws + 20971520L;       //  4,194,304
    float* tagp0 = ws + 25165824L;       // 16,777,216
    float* avgw  = ws + 41943040L;       //      9,216
    float* avgb  = ws + 41952256L;       //          4
    float* ox0   = ws + 41952260L;       //     65,536
    float* oy0   = ws + 42017796L;       //     65,536
    float* ox1   = ws + 42083332L;       //     16,384
    float* oy1   = ws + 42099716L;       //     16,384
    float* nxt1  = tag1;                 // alias: tag1 dead once tagp1 exists

    // 1. averaged offset-conv weights
    k_prep<<<36, 256, 0, stream>>>(offw0, offb0, offw1, offb1, avgw, avgb);
    // 2. level-0 DWT: x (16,64,128,128) -> tag0 (16,256,64,64)
    k_wt<<<16384, 256, 0, stream>>>(x, tag0, 16, 64, 128, 128, 64L * 16384, 16384L);
    // 3. level-1 DWT straight off tag0's LL channels -> tag1 (16,256,32,32)
    k_wt<<<4096, 256, 0, stream>>>(tag0, tag1, 16, 64, 64, 64, 256L * 4096, 4L * 4096);
    // 4. level-1 offsets
    k_off<<<64, 256, 0, stream>>>(tag1, avgw, avgb, 1, ox1, oy1, 16, 32, 32);
    // 5. level-1 snake (sample + dw + relu + pw + scale) -> tagp1
    k_snake<<<dim3(4, 64, 16), 256, 0, stream>>>(tag1, ox1, oy1, dww1, pww1, wsc1, tagp1, 16, 32, 32);
    // 6. level-1 inverse DWT -> nxt1 (16,64,64,64)
    k_iwt<<<4096, 256, 0, stream>>>(tagp1, nxt1, 16, 64, 32, 32);
    // 7. level-0 offsets
    k_off<<<256, 256, 0, stream>>>(tag0, avgw, avgb, 0, ox0, oy0, 16, 64, 64);
    // 8. level-0 snake -> tagp0
    k_snake<<<dim3(16, 64, 16), 256, 0, stream>>>(tag0, ox0, oy0, dww0, pww0, wsc0, tagp0, 16, 64, 64);
    // 9. final: inverse DWT level 0 (+nxt1) + base depthwise conv
    k_final<<<65536, 256, 0, stream>>>(tagp0, nxt1, x, bw, bb, bs, out);
}

// Round 2
// 359.514 us; speedup vs baseline: 2.5417x; 2.5417x over previous
//
#include <hip/hip_runtime.h>

// ---------------- helpers ----------------
static __device__ __forceinline__ float reflectf(float coord, float m) {
    float period = 2.0f * m;
    float c = fmodf(fabsf(coord), period);
    c = (c > m) ? (period - c) : c;
    return fminf(fmaxf(c, 0.0f), m);
}

// ---------------- k_prep: average the 6-channel offset conv into 2 maps ----------------
__global__ __launch_bounds__(256) void k_prep(
    const float* __restrict__ offw0, const float* __restrict__ offb0,
    const float* __restrict__ offw1, const float* __restrict__ offb1,
    float* __restrict__ avgw, float* __restrict__ avgb) {
    int id = blockIdx.x * blockDim.x + threadIdx.x;
    if (id < 2 * 2 * 2304) {
        int l = id / 4608;
        int rem = id % 4608;
        int d = rem / 2304;   // 0 = x-dir (out ch 0..2), 1 = y-dir (out ch 3..5)
        int r = rem % 2304;   // ci*9 + tap
        const float* w = l ? offw1 : offw0;
        float s = w[(d * 3 + 0) * 2304 + r] + w[(d * 3 + 1) * 2304 + r] + w[(d * 3 + 2) * 2304 + r];
        avgw[id] = s * (1.0f / 3.0f);
    }
    if (id == 0) {
        avgb[0] = (offb0[0] + offb0[1] + offb0[2]) * (1.0f / 3.0f);
        avgb[1] = (offb0[3] + offb0[4] + offb0[5]) * (1.0f / 3.0f);
        avgb[2] = (offb1[0] + offb1[1] + offb1[2]) * (1.0f / 3.0f);
        avgb[3] = (offb1[3] + offb1[4] + offb1[5]) * (1.0f / 3.0f);
    }
}

// ---------------- k_wt: Haar DWT, input strided ----------------
__global__ __launch_bounds__(256) void k_wt(
    const float* __restrict__ in, float* __restrict__ tag,
    int B, int C, int H, int W, long sB, long sC) {
    int hh = H >> 1, ww = W >> 1;
    int total = B * C * hh * ww;
    int id = blockIdx.x * blockDim.x + threadIdx.x;
    if (id >= total) return;
    int j = id % ww; int t = id / ww;
    int i = t % hh; t /= hh;
    int c = t % C; int b = t / C;
    const float* p = in + (long)b * sB + (long)c * sC + (long)(2 * i) * W + 2 * j;
    float a0 = p[0], a1 = p[1], a2 = p[W], a3 = p[W + 1];
    float k0 = 0.5f * (a0 + a1 + a2 + a3);
    float k1 = 0.5f * (a0 + a1 - a2 - a3);
    float k2 = 0.5f * (a0 - a1 + a2 - a3);
    float k3 = 0.5f * (a0 - a1 - a2 + a3);
    long os = (long)hh * ww;
    float* o = tag + ((long)b * C * 4 + (long)c * 4) * os + (long)i * ww + j;
    o[0] = k0; o[os] = k1; o[2 * os] = k2; o[3 * os] = k3;
}

// ---------------- k_off_part: partial 256->2 3x3 conv over a 16-channel chunk ----------------
__global__ __launch_bounds__(256) void k_off_part(
    const float* __restrict__ tag, const float* __restrict__ avgw, int level,
    float* __restrict__ part, int B, int hh, int ww) {
    const int CPC = 16;          // channels per chunk
    int chunk = blockIdx.y;      // 0..15
    int npix = hh * ww;
    int totpix = B * npix;
    __shared__ float w[CPC * 18];
    const float* wsrc = avgw + level * 4608;
    int tid = threadIdx.x;
    if (tid < CPC * 9) {
        w[tid] = wsrc[chunk * CPC * 9 + tid];                  // wx
        w[CPC * 9 + tid] = wsrc[2304 + chunk * CPC * 9 + tid]; // wy
    }
    __syncthreads();
    int id = blockIdx.x * 256 + tid;
    if (id >= totpix) return;
    int j = id % ww; int t = id / ww;
    int i = t % hh; int b = t / hh;
    float ax = 0.f, ay = 0.f;
    const float* base = tag + ((long)b * 256 + chunk * CPC) * (long)npix;
    for (int cc = 0; cc < CPC; cc++) {
        const float* pc = base + (long)cc * npix;
        const float* wx = w + cc * 9;
        const float* wy = w + CPC * 9 + cc * 9;
        #pragma unroll
        for (int di = 0; di < 3; di++) {
            int y = i + di - 1;
            if ((unsigned)y >= (unsigned)hh) continue;
            #pragma unroll
            for (int dj = 0; dj < 3; dj++) {
                int x = j + dj - 1;
                if ((unsigned)x >= (unsigned)ww) continue;
                float v = pc[y * ww + x];
                ax = fmaf(v, wx[di * 3 + dj], ax);
                ay = fmaf(v, wy[di * 3 + dj], ay);
            }
        }
    }
    part[((long)0 * 16 + chunk) * totpix + id] = ax;
    part[((long)1 * 16 + chunk) * totpix + id] = ay;
}

// ---------------- k_off_red: reduce 16 chunks + bias ----------------
__global__ __launch_bounds__(256) void k_off_red(
    const float* __restrict__ part, const float* __restrict__ avgb, int level,
    float* __restrict__ ox, float* __restrict__ oy, int totpix) {
    int id = blockIdx.x * 256 + threadIdx.x;
    if (id >= totpix) return;
    float sx = avgb[level * 2 + 0], sy = avgb[level * 2 + 1];
    #pragma unroll
    for (int c = 0; c < 16; c++) sx += part[(long)c * totpix + id];
    #pragma unroll
    for (int c = 0; c < 16; c++) sy += part[((long)16 + c) * totpix + id];
    ox[id] = sx; oy[id] = sy;
}

// ---------------- k_snake: grid-sample (reflect) -> LDS tile -> dw3x3+ReLU -> grouped 1x1 -> scale ----------------
__global__ __launch_bounds__(256) void k_snake(
    const float* __restrict__ tag,
    const float* __restrict__ ox, const float* __restrict__ oy,
    const float* __restrict__ dww, const float* __restrict__ pww,
    const float* __restrict__ wsc,
    float* __restrict__ out, int B, int hh, int ww) {
    __shared__ float s[4][18][18];
    __shared__ float dwW[36];
    __shared__ float pwW[16];
    __shared__ float wscW[4];
    int tilesX = ww >> 4;
    int tile = blockIdx.x;
    int g = blockIdx.y;
    int b = blockIdx.z;
    int i0 = (tile / tilesX) * 16;
    int j0 = (tile % tilesX) * 16;
    int tid = threadIdx.x;
    if (tid < 36) dwW[tid] = dww[g * 36 + tid];
    else if (tid < 52) pwW[tid - 36] = pww[g * 16 + (tid - 36)];
    else if (tid < 56) wscW[tid - 52] = wsc[g * 4 + (tid - 52)];
    int npix = hh * ww;
    const float* tb = tag + ((long)b * 256 + (long)g * 4) * npix;
    const float* oxb = ox + (long)b * npix;
    const float* oyb = oy + (long)b * npix;
    float mW = (float)(ww - 1), mH = (float)(hh - 1);
    for (int p = tid; p < 324; p += 256) {
        int ty = p / 18, tx = p % 18;
        int y = i0 - 1 + ty, x = j0 - 1 + tx;
        float v0 = 0.f, v1 = 0.f, v2 = 0.f, v3 = 0.f;
        if ((unsigned)y < (unsigned)hh && (unsigned)x < (unsigned)ww) {
            float px = (float)x + oxb[y * ww + x];
            float py = (float)y + oyb[y * ww + x];
            px = reflectf(px, mW);
            py = reflectf(py, mH);
            float x0f = floorf(px), y0f = floorf(py);
            float fx = px - x0f, fy = py - y0f;
            int x0 = min(max((int)x0f, 0), ww - 1);
            int y0 = min(max((int)y0f, 0), hh - 1);
            int x1 = min(x0 + 1, ww - 1);
            int y1 = min(y0 + 1, hh - 1);
            float w00 = (1.f - fx) * (1.f - fy), w01 = fx * (1.f - fy);
            float w10 = (1.f - fx) * fy,         w11 = fx * fy;
            int i00 = y0 * ww + x0, i01 = y0 * ww + x1;
            int i10 = y1 * ww + x0, i11 = y1 * ww + x1;
            const float* c0 = tb;
            const float* c1 = tb + npix;
            const float* c2 = tb + 2 * (long)npix;
            const float* c3 = tb + 3 * (long)npix;
            v0 = c0[i00] * w00 + c0[i01] * w01 + c0[i10] * w10 + c0[i11] * w11;
            v1 = c1[i00] * w00 + c1[i01] * w01 + c1[i10] * w10 + c1[i11] * w11;
            v2 = c2[i00] * w00 + c2[i01] * w01 + c2[i10] * w10 + c2[i11] * w11;
            v3 = c3[i00] * w00 + c3[i01] * w01 + c3[i10] * w10 + c3[i11] * w11;
        }
        s[0][ty][tx] = v0;
        s[1][ty][tx] = v1;
        s[2][ty][tx] = v2;
        s[3][ty][tx] = v3;
    }
    __syncthreads();
    int ti = tid >> 4, tj = tid & 15;
    int i = i0 + ti, j = j0 + tj;
    float r[4];
    #pragma unroll
    for (int cc = 0; cc < 4; cc++) {
        float acc = 0.f;
        #pragma unroll
        for (int di = 0; di < 3; di++)
            #pragma unroll
            for (int dj = 0; dj < 3; dj++)
                acc = fmaf(s[cc][ti + di][tj + dj], dwW[cc * 9 + di * 3 + dj], acc);
        r[cc] = fmaxf(acc, 0.f);
    }
    #pragma unroll
    for (int oo = 0; oo < 4; oo++) {
        float o = r[0] * pwW[oo * 4 + 0] + r[1] * pwW[oo * 4 + 1]
                + r[2] * pwW[oo * 4 + 2] + r[3] * pwW[oo * 4 + 3];
        out[(((long)b * 256 + (long)g * 4 + oo) * npix) + (long)i * ww + j] = o * wscW[oo];
    }
}

// ---------------- k_iwt: inverse Haar (level 1) ----------------
__global__ __launch_bounds__(256) void k_iwt(
    const float* __restrict__ coef, float* __restrict__ out,
    int B, int C, int hh, int ww) {
    int total = B * C * hh * ww;
    int id = blockIdx.x * blockDim.x + threadIdx.x;
    if (id >= total) return;
    int j = id % ww; int t = id / ww;
    int i = t % hh; t /= hh;
    int c = t % C; int b = t / C;
    long npix = (long)hh * ww;
    const float* p = coef + ((long)b * C * 4 + (long)c * 4) * npix + (long)i * ww + j;
    float c0 = p[0], c1 = p[npix], c2 = p[2 * npix], c3 = p[3 * npix];
    int W2 = ww * 2;
    float* o = out + (((long)b * C + c) * (2 * (long)hh) + 2 * i) * W2 + 2 * j;
    o[0]      = 0.5f * (c0 + c1 + c2 + c3);
    o[1]      = 0.5f * (c0 + c1 - c2 - c3);
    o[W2]     = 0.5f * (c0 - c1 + c2 - c3);
    o[W2 + 1] = 0.5f * (c0 - c1 - c2 + c3);
}

// ---------------- k_final: level-0 inverse Haar (+nxt1) + base depthwise conv + add ----------------
__global__ __launch_bounds__(256) void k_final(
    const float* __restrict__ tagp0, const float* __restrict__ nxt1,
    const float* __restrict__ x,
    const float* __restrict__ bw, const float* __restrict__ bb,
    const float* __restrict__ bs, float* __restrict__ out) {
    const int W = 128, H = 128, C = 64, hh = 64, ww = 64;
    int id = blockIdx.x * blockDim.x + threadIdx.x;
    if (id >= 16 * C * H * W) return;
    int xx = id % W; int t = id / W;
    int yy = t % H; t /= H;
    int c = t % C; int b = t / C;
    int i = yy >> 1, j = xx >> 1, dy = yy & 1, dx = xx & 1;
    long npix = (long)hh * ww;
    const float* p = tagp0 + ((long)b * 256 + (long)c * 4) * npix + (long)i * ww + j;
    float c0 = p[0] + nxt1[(((long)b * C + c) * hh + i) * ww + j];
    float c1 = p[npix], c2 = p[2 * npix], c3 = p[3 * npix];
    float s1 = dy ? -1.f : 1.f;
    float s2 = dx ? -1.f : 1.f;
    float rec = 0.5f * (c0 + s1 * c1 + s2 * c2 + s1 * s2 * c3);
    float acc = bb[c];
    const float* xb = x + ((long)b * C + c) * (long)(H * W);
    const float* wb = bw + c * 9;
    #pragma unroll
    for (int di = 0; di < 3; di++) {
        int y2 = yy + di - 1;
        if ((unsigned)y2 >= (unsigned)H) continue;
        #pragma unroll
        for (int dj = 0; dj < 3; dj++) {
            int x2 = xx + dj - 1;
            if ((unsigned)x2 >= (unsigned)W) continue;
            acc = fmaf(xb[y2 * W + x2], wb[di * 3 + dj], acc);
        }
    }
    out[id] = bs[c] * acc + rec;
}

// ---------------- launch ----------------
extern "C" void kernel_launch(void* const* d_in, const int* in_sizes, int n_in,
                              void* d_out, int out_size, void* d_ws, size_t ws_size,
                              hipStream_t stream) {
    const float* x     = (const float*)d_in[0];
    const float* bw    = (const float*)d_in[1];
    const float* bb    = (const float*)d_in[2];
    const float* bs    = (const float*)d_in[3];
    const float* offw0 = (const float*)d_in[4];
    const float* offb0 = (const float*)d_in[5];
    const float* dww0  = (const float*)d_in[6];
    const float* pww0  = (const float*)d_in[7];
    const float* wsc0  = (const float*)d_in[8];
    const float* offw1 = (const float*)d_in[9];
    const float* offb1 = (const float*)d_in[10];
    const float* dww1  = (const float*)d_in[11];
    const float* pww1  = (const float*)d_in[12];
    const float* wsc1  = (const float*)d_in[13];
    float* out = (float*)d_out;
    float* ws = (float*)d_ws;

    // workspace layout (floats)
    float* tag0  = ws + 0L;              // 16,777,216
    float* tag1  = ws + 16777216L;       //  4,194,304  (aliased as nxt1 later)
    float* tagp1 = ws + 20971520L;       //  4,194,304  (aliased as part1 before k_snake1)
    float* tagp0 = ws + 25165824L;       // 16,777,216  (aliased as part0 before k_snake0)
    float* avgw  = ws + 41943040L;       //      9,216
    float* avgb  = ws + 41952256L;       //          4
    float* ox0   = ws + 41952260L;       //     65,536
    float* oy0   = ws + 42017796L;       //     65,536
    float* ox1   = ws + 42083332L;       //     16,384
    float* oy1   = ws + 42099716L;       //     16,384
    float* nxt1  = tag1;                 // tag1 dead once tagp1 exists
    float* part1 = tagp1;                // needs 2*16*16384 = 524,288 <= 4,194,304
    float* part0 = tagp0;                // needs 2*16*65536 = 2,097,152 <= 16,777,216

    // 1. averaged offset-conv weights
    k_prep<<<36, 256, 0, stream>>>(offw0, offb0, offw1, offb1, avgw, avgb);
    // 2. level-0 DWT: x (16,64,128,128) -> tag0 (16,256,64,64)
    k_wt<<<16384, 256, 0, stream>>>(x, tag0, 16, 64, 128, 128, 64L * 16384, 16384L);
    // 3. level-1 DWT straight off tag0's LL channels -> tag1 (16,256,32,32)
    k_wt<<<4096, 256, 0, stream>>>(tag0, tag1, 16, 64, 64, 64, 256L * 4096, 4L * 4096);
    // 4. level-1 offsets (chunked + reduce)
    k_off_part<<<dim3(64, 16), 256, 0, stream>>>(tag1, avgw, 1, part1, 16, 32, 32);
    k_off_red<<<64, 256, 0, stream>>>(part1, avgb, 1, ox1, oy1, 16384);
    // 5. level-1 snake -> tagp1
    k_snake<<<dim3(4, 64, 16), 256, 0, stream>>>(tag1, ox1, oy1, dww1, pww1, wsc1, tagp1, 16, 32, 32);
    // 6. level-1 inverse DWT -> nxt1 (16,64,64,64)
    k_iwt<<<4096, 256, 0, stream>>>(tagp1, nxt1, 16, 64, 32, 32);
    // 7. level-0 offsets (chunked + reduce)
    k_off_part<<<dim3(256, 16), 256, 0, stream>>>(tag0, avgw, 0, part0, 16, 64, 64);
    k_off_red<<<256, 256, 0, stream>>>(part0, avgb, 0, ox0, oy0, 65536);
    // 8. level-0 snake -> tagp0
    k_snake<<<dim3(16, 64, 16), 256, 0, stream>>>(tag0, ox0, oy0, dww0, pww0, wsc0, tagp0, 16, 64, 64);
    // 9. final: inverse DWT level 0 (+nxt1) + base depthwise conv
    k_final<<<65536, 256, 0, stream>>>(tagp0, nxt1, x, bw, bb, bs, out);
}

// Round 3
// 236.788 us; speedup vs baseline: 3.8591x; 1.5183x over previous
//
#include <hip/hip_runtime.h>

// ---------------- helpers ----------------
static __device__ __forceinline__ float reflectf(float coord, float m) {
    float period = 2.0f * m;
    float c = fmodf(fabsf(coord), period);
    c = (c > m) ? (period - c) : c;
    return fminf(fmaxf(c, 0.0f), m);
}

// ---------------- k_prep ----------------
__global__ __launch_bounds__(256) void k_prep(
    const float* __restrict__ offw0, const float* __restrict__ offb0,
    const float* __restrict__ offw1, const float* __restrict__ offb1,
    float* __restrict__ avgw, float* __restrict__ avgb) {
    int id = blockIdx.x * blockDim.x + threadIdx.x;
    if (id < 2 * 2 * 2304) {
        int l = id / 4608;
        int rem = id % 4608;
        int d = rem / 2304;
        int r = rem % 2304;
        const float* w = l ? offw1 : offw0;
        float s = w[(d * 3 + 0) * 2304 + r] + w[(d * 3 + 1) * 2304 + r] + w[(d * 3 + 2) * 2304 + r];
        avgw[id] = s * (1.0f / 3.0f);
    }
    if (id == 0) {
        avgb[0] = (offb0[0] + offb0[1] + offb0[2]) * (1.0f / 3.0f);
        avgb[1] = (offb0[3] + offb0[4] + offb0[5]) * (1.0f / 3.0f);
        avgb[2] = (offb1[0] + offb1[1] + offb1[2]) * (1.0f / 3.0f);
        avgb[3] = (offb1[3] + offb1[4] + offb1[5]) * (1.0f / 3.0f);
    }
}

// ---------------- k_wt0: x NCHW -> tag0v [b][64][64][64][4] ----------------
__global__ __launch_bounds__(256) void k_wt0(
    const float* __restrict__ x, float4* __restrict__ tagv) {
    int id = blockIdx.x * 256 + threadIdx.x;
    if (id >= 16 * 64 * 64 * 64) return;
    int j = id & 63; int t = id >> 6;
    int i = t & 63; t >>= 6;
    int c = t & 63; int b = t >> 6;
    const float* p = x + (((long)(b * 64 + c) * 128) + 2 * i) * 128 + 2 * j;
    float2 r0 = *(const float2*)p;
    float2 r1 = *(const float2*)(p + 128);
    float a0 = r0.x, a1 = r0.y, a2 = r1.x, a3 = r1.y;
    float4 o;
    o.x = 0.5f * (a0 + a1 + a2 + a3);
    o.y = 0.5f * (a0 + a1 - a2 - a3);
    o.z = 0.5f * (a0 - a1 + a2 - a3);
    o.w = 0.5f * (a0 - a1 - a2 + a3);
    tagv[id] = o;
}

// ---------------- k_wt1: tag0v comp0 (LL) -> tag1v [b][64][32][32][4] ----------------
__global__ __launch_bounds__(256) void k_wt1(
    const float* __restrict__ tag0, float4* __restrict__ tag1v) {
    int id = blockIdx.x * 256 + threadIdx.x;
    if (id >= 16 * 64 * 32 * 32) return;
    int j = id & 31; int t = id >> 5;
    int i = t & 31; t >>= 5;
    int c = t & 63; int b = t >> 6;
    const float* base = tag0 + ((((long)(b * 64 + c) * 64) + 2 * i) * 64 + 2 * j) * 4;
    float a0 = base[0], a1 = base[4], a2 = base[256], a3 = base[260];
    float4 o;
    o.x = 0.5f * (a0 + a1 + a2 + a3);
    o.y = 0.5f * (a0 + a1 - a2 - a3);
    o.z = 0.5f * (a0 - a1 + a2 - a3);
    o.w = 0.5f * (a0 - a1 - a2 + a3);
    tag1v[id] = o;
}

// ---------------- k_off_part: partial 256->2 3x3 conv, vec4 groups ----------------
__global__ __launch_bounds__(256) void k_off_part(
    const float4* __restrict__ tagv, const float* __restrict__ avgw, int level,
    float* __restrict__ part, int B, int hh, int ww) {
    int chunk = blockIdx.y;          // 0..15 -> groups chunk*4..+3 (= channels chunk*16..+15)
    int npix = hh * ww;
    int totpix = B * npix;
    __shared__ float wls[2][4][9][4];   // [dir][gg][tap][comp]
    const float* wsrc = avgw + level * 4608;
    int tid = threadIdx.x;
    if (tid < 288) {
        int d = tid / 144, rem = tid % 144;
        int gg = rem / 36; int tap = (rem % 36) / 4; int cc = tid & 3;
        wls[d][gg][tap][cc] = wsrc[d * 2304 + (chunk * 16 + gg * 4 + cc) * 9 + tap];
    }
    __syncthreads();
    int id = blockIdx.x * 256 + tid;
    if (id >= totpix) return;
    int j = id % ww; int t = id / ww;
    int i = t % hh; int b = t / hh;
    float ax = 0.f, ay = 0.f;
    #pragma unroll
    for (int gg = 0; gg < 4; gg++) {
        const float4* pg = tagv + ((long)b * 64 + chunk * 4 + gg) * npix;
        #pragma unroll
        for (int di = 0; di < 3; di++) {
            int y = i + di - 1;
            if ((unsigned)y >= (unsigned)hh) continue;
            #pragma unroll
            for (int dj = 0; dj < 3; dj++) {
                int x = j + dj - 1;
                if ((unsigned)x >= (unsigned)ww) continue;
                float4 v = pg[y * ww + x];
                const float* wx = &wls[0][gg][di * 3 + dj][0];
                const float* wy = &wls[1][gg][di * 3 + dj][0];
                ax = fmaf(v.x, wx[0], ax); ax = fmaf(v.y, wx[1], ax);
                ax = fmaf(v.z, wx[2], ax); ax = fmaf(v.w, wx[3], ax);
                ay = fmaf(v.x, wy[0], ay); ay = fmaf(v.y, wy[1], ay);
                ay = fmaf(v.z, wy[2], ay); ay = fmaf(v.w, wy[3], ay);
            }
        }
    }
    part[((long)0 * 16 + chunk) * totpix + id] = ax;
    part[((long)1 * 16 + chunk) * totpix + id] = ay;
}

// ---------------- k_off_red ----------------
__global__ __launch_bounds__(256) void k_off_red(
    const float* __restrict__ part, const float* __restrict__ avgb, int level,
    float* __restrict__ ox, float* __restrict__ oy, int totpix) {
    int id = blockIdx.x * 256 + threadIdx.x;
    if (id >= totpix) return;
    float sx = avgb[level * 2 + 0], sy = avgb[level * 2 + 1];
    #pragma unroll
    for (int c = 0; c < 16; c++) sx += part[(long)c * totpix + id];
    #pragma unroll
    for (int c = 0; c < 16; c++) sy += part[((long)16 + c) * totpix + id];
    ox[id] = sx; oy[id] = sy;
}

// ---------------- k_snake: vec4 gather -> LDS -> dw3x3+ReLU -> pw -> scale ----------------
__global__ __launch_bounds__(256) void k_snake(
    const float4* __restrict__ tagv,
    const float* __restrict__ ox, const float* __restrict__ oy,
    const float* __restrict__ dww, const float* __restrict__ pww,
    const float* __restrict__ wsc,
    float4* __restrict__ outv, int B, int hh, int ww) {
    __shared__ float s[4][18][18];
    __shared__ float dwW[36];
    __shared__ float pwW[16];
    __shared__ float wscW[4];
    int tilesX = ww >> 4;
    int tile = blockIdx.x;
    int g = blockIdx.y;
    int b = blockIdx.z;
    int i0 = (tile / tilesX) * 16;
    int j0 = (tile % tilesX) * 16;
    int tid = threadIdx.x;
    if (tid < 36) dwW[tid] = dww[g * 36 + tid];
    else if (tid < 52) pwW[tid - 36] = pww[g * 16 + (tid - 36)];
    else if (tid < 56) wscW[tid - 52] = wsc[g * 4 + (tid - 52)];
    int npix = hh * ww;
    const float4* tb = tagv + ((long)b * 64 + g) * npix;
    const float* oxb = ox + (long)b * npix;
    const float* oyb = oy + (long)b * npix;
    float mW = (float)(ww - 1), mH = (float)(hh - 1);
    for (int p = tid; p < 324; p += 256) {
        int ty = p / 18, tx = p % 18;
        int y = i0 - 1 + ty, x = j0 - 1 + tx;
        float4 v = make_float4(0.f, 0.f, 0.f, 0.f);
        if ((unsigned)y < (unsigned)hh && (unsigned)x < (unsigned)ww) {
            float px = (float)x + oxb[y * ww + x];
            float py = (float)y + oyb[y * ww + x];
            px = reflectf(px, mW);
            py = reflectf(py, mH);
            float x0f = floorf(px), y0f = floorf(py);
            float fx = px - x0f, fy = py - y0f;
            int x0 = min(max((int)x0f, 0), ww - 1);
            int y0 = min(max((int)y0f, 0), hh - 1);
            int x1 = min(x0 + 1, ww - 1);
            int y1 = min(y0 + 1, hh - 1);
            float w00 = (1.f - fx) * (1.f - fy), w01 = fx * (1.f - fy);
            float w10 = (1.f - fx) * fy,         w11 = fx * fy;
            float4 v00 = tb[y0 * ww + x0], v01 = tb[y0 * ww + x1];
            float4 v10 = tb[y1 * ww + x0], v11 = tb[y1 * ww + x1];
            v.x = v00.x * w00 + v01.x * w01 + v10.x * w10 + v11.x * w11;
            v.y = v00.y * w00 + v01.y * w01 + v10.y * w10 + v11.y * w11;
            v.z = v00.z * w00 + v01.z * w01 + v10.z * w10 + v11.z * w11;
            v.w = v00.w * w00 + v01.w * w01 + v10.w * w10 + v11.w * w11;
        }
        s[0][ty][tx] = v.x;
        s[1][ty][tx] = v.y;
        s[2][ty][tx] = v.z;
        s[3][ty][tx] = v.w;
    }
    __syncthreads();
    int ti = tid >> 4, tj = tid & 15;
    int i = i0 + ti, j = j0 + tj;
    float r[4];
    #pragma unroll
    for (int cc = 0; cc < 4; cc++) {
        float acc = 0.f;
        #pragma unroll
        for (int di = 0; di < 3; di++)
            #pragma unroll
            for (int dj = 0; dj < 3; dj++)
                acc = fmaf(s[cc][ti + di][tj + dj], dwW[cc * 9 + di * 3 + dj], acc);
        r[cc] = fmaxf(acc, 0.f);
    }
    float4 o;
    o.x = (r[0] * pwW[0]  + r[1] * pwW[1]  + r[2] * pwW[2]  + r[3] * pwW[3])  * wscW[0];
    o.y = (r[0] * pwW[4]  + r[1] * pwW[5]  + r[2] * pwW[6]  + r[3] * pwW[7])  * wscW[1];
    o.z = (r[0] * pwW[8]  + r[1] * pwW[9]  + r[2] * pwW[10] + r[3] * pwW[11]) * wscW[2];
    o.w = (r[0] * pwW[12] + r[1] * pwW[13] + r[2] * pwW[14] + r[3] * pwW[15]) * wscW[3];
    outv[((long)b * 64 + g) * npix + (long)i * ww + j] = o;
}

// ---------------- k_iwt: inverse Haar (level 1), vec4 in, float2 out ----------------
__global__ __launch_bounds__(256) void k_iwt(
    const float4* __restrict__ coefv, float* __restrict__ out,
    int B, int hh, int ww) {
    int total = B * 64 * hh * ww;
    int id = blockIdx.x * 256 + threadIdx.x;
    if (id >= total) return;
    int j = id % ww; int t = id / ww;
    int i = t % hh; t /= hh;
    int c = t & 63; int b = t >> 6;
    float4 cf = coefv[id];
    int W2 = ww * 2;
    float* o = out + (((long)(b * 64 + c) * (2 * hh)) + 2 * i) * W2 + 2 * j;
    *(float2*)o        = make_float2(0.5f * (cf.x + cf.y + cf.z + cf.w),
                                     0.5f * (cf.x + cf.y - cf.z - cf.w));
    *(float2*)(o + W2) = make_float2(0.5f * (cf.x - cf.y + cf.z - cf.w),
                                     0.5f * (cf.x - cf.y - cf.z + cf.w));
}

// ---------------- k_final: LDS-tiled base conv + level-0 inverse Haar (+nxt1) ----------------
__global__ __launch_bounds__(256) void k_final(
    const float4* __restrict__ tagp0v, const float* __restrict__ nxt1,
    const float* __restrict__ x,
    const float* __restrict__ bw, const float* __restrict__ bb,
    const float* __restrict__ bs, float* __restrict__ out) {
    int blk = blockIdx.x;
    int tile = blk & 15; int c = (blk >> 4) & 63; int b = blk >> 10;
    int ty0 = (tile >> 2) * 32, tx0 = (tile & 3) * 32;
    __shared__ float xs[34][36];
    const float* xb = x + (long)(b * 64 + c) * 16384;
    int tid = threadIdx.x;
    for (int p = tid; p < 34 * 34; p += 256) {
        int r = p / 34, q = p % 34;
        int y = ty0 - 1 + r, xg = tx0 - 1 + q;
        float v = 0.f;
        if ((unsigned)y < 128u && (unsigned)xg < 128u) v = xb[y * 128 + xg];
        xs[r][q] = v;
    }
    float w0 = bw[c * 9 + 0], w1 = bw[c * 9 + 1], w2 = bw[c * 9 + 2];
    float w3 = bw[c * 9 + 3], w4 = bw[c * 9 + 4], w5 = bw[c * 9 + 5];
    float w6 = bw[c * 9 + 6], w7 = bw[c * 9 + 7], w8 = bw[c * 9 + 8];
    float bias = bb[c], scale = bs[c];
    __syncthreads();
    int ti = tid >> 4, tj = tid & 15;
    int yy = ty0 + 2 * ti, xx = tx0 + 2 * tj;
    int i = yy >> 1, j = xx >> 1;
    long cidx = (((long)(b * 64 + c) * 64) + i) * 64 + j;
    float4 cf = tagp0v[cidx];
    float c0 = cf.x + nxt1[cidx];
    float c1 = cf.y, c2 = cf.z, c3 = cf.w;
    float rec00 = 0.5f * (c0 + c1 + c2 + c3);
    float rec01 = 0.5f * (c0 + c1 - c2 - c3);
    float rec10 = 0.5f * (c0 - c1 + c2 - c3);
    float rec11 = 0.5f * (c0 - c1 - c2 + c3);
    float o00, o01, o10, o11;
    {
        int a = 2 * ti, bq = 2 * tj;
        #define CONV(dy,dx) ({ \
            float acc = bias; \
            acc = fmaf(xs[a+dy+0][bq+dx+0], w0, acc); \
            acc = fmaf(xs[a+dy+0][bq+dx+1], w1, acc); \
            acc = fmaf(xs[a+dy+0][bq+dx+2], w2, acc); \
            acc = fmaf(xs[a+dy+1][bq+dx+0], w3, acc); \
            acc = fmaf(xs[a+dy+1][bq+dx+1], w4, acc); \
            acc = fmaf(xs[a+dy+1][bq+dx+2], w5, acc); \
            acc = fmaf(xs[a+dy+2][bq+dx+0], w6, acc); \
            acc = fmaf(xs[a+dy+2][bq+dx+1], w7, acc); \
            acc = fmaf(xs[a+dy+2][bq+dx+2], w8, acc); \
            acc; })
        o00 = scale * CONV(0,0) + rec00;
        o01 = scale * CONV(0,1) + rec01;
        o10 = scale * CONV(1,0) + rec10;
        o11 = scale * CONV(1,1) + rec11;
        #undef CONV
    }
    float* ob = out + (((long)(b * 64 + c) * 128) + yy) * 128 + xx;
    *(float2*)ob         = make_float2(o00, o01);
    *(float2*)(ob + 128) = make_float2(o10, o11);
}

// ---------------- launch ----------------
extern "C" void kernel_launch(void* const* d_in, const int* in_sizes, int n_in,
                              void* d_out, int out_size, void* d_ws, size_t ws_size,
                              hipStream_t stream) {
    const float* x     = (const float*)d_in[0];
    const float* bw    = (const float*)d_in[1];
    const float* bb    = (const float*)d_in[2];
    const float* bs    = (const float*)d_in[3];
    const float* offw0 = (const float*)d_in[4];
    const float* offb0 = (const float*)d_in[5];
    const float* dww0  = (const float*)d_in[6];
    const float* pww0  = (const float*)d_in[7];
    const float* wsc0  = (const float*)d_in[8];
    const float* offw1 = (const float*)d_in[9];
    const float* offb1 = (const float*)d_in[10];
    const float* dww1  = (const float*)d_in[11];
    const float* pww1  = (const float*)d_in[12];
    const float* wsc1  = (const float*)d_in[13];
    float* out = (float*)d_out;
    float* ws = (float*)d_ws;

    // workspace layout (floats) — vec4 layouts: [b][64][h][w][4]
    float* tag0  = ws + 0L;              // 16,777,216
    float* tag1  = ws + 16777216L;       //  4,194,304  (aliased as nxt1 later)
    float* tagp1 = ws + 20971520L;       //  4,194,304  (aliased as part1 first)
    float* tagp0 = ws + 25165824L;       // 16,777,216  (aliased as part0 first)
    float* avgw  = ws + 41943040L;       //      9,216
    float* avgb  = ws + 41952256L;       //          4
    float* ox0   = ws + 41952260L;       //     65,536
    float* oy0   = ws + 42017796L;       //     65,536
    float* ox1   = ws + 42083332L;       //     16,384
    float* oy1   = ws + 42099716L;       //     16,384
    float* nxt1  = tag1;
    float* part1 = tagp1;
    float* part0 = tagp0;

    k_prep<<<36, 256, 0, stream>>>(offw0, offb0, offw1, offb1, avgw, avgb);
    // level-0 DWT: x -> tag0v
    k_wt0<<<16384, 256, 0, stream>>>(x, (float4*)tag0);
    // level-1 DWT off tag0v LL -> tag1v
    k_wt1<<<4096, 256, 0, stream>>>(tag0, (float4*)tag1);
    // level-1 offsets
    k_off_part<<<dim3(64, 16), 256, 0, stream>>>((const float4*)tag1, avgw, 1, part1, 16, 32, 32);
    k_off_red<<<64, 256, 0, stream>>>(part1, avgb, 1, ox1, oy1, 16384);
    // level-1 snake -> tagp1v
    k_snake<<<dim3(4, 64, 16), 256, 0, stream>>>((const float4*)tag1, ox1, oy1, dww1, pww1, wsc1,
                                                 (float4*)tagp1, 16, 32, 32);
    // level-1 inverse DWT -> nxt1
    k_iwt<<<4096, 256, 0, stream>>>((const float4*)tagp1, nxt1, 16, 32, 32);
    // level-0 offsets
    k_off_part<<<dim3(256, 16), 256, 0, stream>>>((const float4*)tag0, avgw, 0, part0, 16, 64, 64);
    k_off_red<<<256, 256, 0, stream>>>(part0, avgb, 0, ox0, oy0, 65536);
    // level-0 snake -> tagp0v
    k_snake<<<dim3(16, 64, 16), 256, 0, stream>>>((const float4*)tag0, ox0, oy0, dww0, pww0, wsc0,
                                                  (float4*)tagp0, 16, 64, 64);
    // final
    k_final<<<16384, 256, 0, stream>>>((const float4*)tagp0, nxt1, x, bw, bb, bs, out);
}

// Round 4
// 230.614 us; speedup vs baseline: 3.9624x; 1.0268x over previous
//
#include <hip/hip_runtime.h>

// ---------------- helpers ----------------
static __device__ __forceinline__ float reflectf(float coord, float m) {
    float period = 2.0f * m;
    float c = fmodf(fabsf(coord), period);
    c = (c > m) ? (period - c) : c;
    return fminf(fmaxf(c, 0.0f), m);
}

// ---------------- k_prep ----------------
__global__ __launch_bounds__(256) void k_prep(
    const float* __restrict__ offw0, const float* __restrict__ offb0,
    const float* __restrict__ offw1, const float* __restrict__ offb1,
    float* __restrict__ avgw, float* __restrict__ avgb) {
    int id = blockIdx.x * blockDim.x + threadIdx.x;
    if (id < 2 * 2 * 2304) {
        int l = id / 4608;
        int rem = id % 4608;
        int d = rem / 2304;
        int r = rem % 2304;
        const float* w = l ? offw1 : offw0;
        float s = w[(d * 3 + 0) * 2304 + r] + w[(d * 3 + 1) * 2304 + r] + w[(d * 3 + 2) * 2304 + r];
        avgw[id] = s * (1.0f / 3.0f);
    }
    if (id == 0) {
        avgb[0] = (offb0[0] + offb0[1] + offb0[2]) * (1.0f / 3.0f);
        avgb[1] = (offb0[3] + offb0[4] + offb0[5]) * (1.0f / 3.0f);
        avgb[2] = (offb1[0] + offb1[1] + offb1[2]) * (1.0f / 3.0f);
        avgb[3] = (offb1[3] + offb1[4] + offb1[5]) * (1.0f / 3.0f);
    }
}

// ---------------- k_wt0: x NCHW -> tag0v [b][64][64][64][4] ----------------
__global__ __launch_bounds__(256) void k_wt0(
    const float* __restrict__ x, float4* __restrict__ tagv) {
    int id = blockIdx.x * 256 + threadIdx.x;
    if (id >= 16 * 64 * 64 * 64) return;
    int j = id & 63; int t = id >> 6;
    int i = t & 63; t >>= 6;
    int c = t & 63; int b = t >> 6;
    const float* p = x + (((long)(b * 64 + c) * 128) + 2 * i) * 128 + 2 * j;
    float2 r0 = *(const float2*)p;
    float2 r1 = *(const float2*)(p + 128);
    float a0 = r0.x, a1 = r0.y, a2 = r1.x, a3 = r1.y;
    float4 o;
    o.x = 0.5f * (a0 + a1 + a2 + a3);
    o.y = 0.5f * (a0 + a1 - a2 - a3);
    o.z = 0.5f * (a0 - a1 + a2 - a3);
    o.w = 0.5f * (a0 - a1 - a2 + a3);
    tagv[id] = o;
}

// ---------------- k_wt1: tag0v comp0 (LL) -> tag1v [b][64][32][32][4] ----------------
__global__ __launch_bounds__(256) void k_wt1(
    const float* __restrict__ tag0, float4* __restrict__ tag1v) {
    int id = blockIdx.x * 256 + threadIdx.x;
    if (id >= 16 * 64 * 32 * 32) return;
    int j = id & 31; int t = id >> 5;
    int i = t & 31; t >>= 5;
    int c = t & 63; int b = t >> 6;
    const float* base = tag0 + ((((long)(b * 64 + c) * 64) + 2 * i) * 64 + 2 * j) * 4;
    float a0 = base[0], a1 = base[4], a2 = base[256], a3 = base[260];
    float4 o;
    o.x = 0.5f * (a0 + a1 + a2 + a3);
    o.y = 0.5f * (a0 + a1 - a2 - a3);
    o.z = 0.5f * (a0 - a1 + a2 - a3);
    o.w = 0.5f * (a0 - a1 - a2 + a3);
    tag1v[id] = o;
}

// ---------------- k_off_part ----------------
__global__ __launch_bounds__(256) void k_off_part(
    const float4* __restrict__ tagv, const float* __restrict__ avgw, int level,
    float* __restrict__ part, int B, int hh, int ww) {
    int chunk = blockIdx.y;
    int npix = hh * ww;
    int totpix = B * npix;
    __shared__ float wls[2][4][9][4];
    const float* wsrc = avgw + level * 4608;
    int tid = threadIdx.x;
    if (tid < 288) {
        int d = tid / 144, rem = tid % 144;
        int gg = rem / 36; int tap = (rem % 36) / 4; int cc = tid & 3;
        wls[d][gg][tap][cc] = wsrc[d * 2304 + (chunk * 16 + gg * 4 + cc) * 9 + tap];
    }
    __syncthreads();
    int id = blockIdx.x * 256 + tid;
    if (id >= totpix) return;
    int j = id % ww; int t = id / ww;
    int i = t % hh; int b = t / hh;
    float ax = 0.f, ay = 0.f;
    #pragma unroll
    for (int gg = 0; gg < 4; gg++) {
        const float4* pg = tagv + ((long)b * 64 + chunk * 4 + gg) * npix;
        #pragma unroll
        for (int di = 0; di < 3; di++) {
            int y = i + di - 1;
            if ((unsigned)y >= (unsigned)hh) continue;
            #pragma unroll
            for (int dj = 0; dj < 3; dj++) {
                int x = j + dj - 1;
                if ((unsigned)x >= (unsigned)ww) continue;
                float4 v = pg[y * ww + x];
                const float* wx = &wls[0][gg][di * 3 + dj][0];
                const float* wy = &wls[1][gg][di * 3 + dj][0];
                ax = fmaf(v.x, wx[0], ax); ax = fmaf(v.y, wx[1], ax);
                ax = fmaf(v.z, wx[2], ax); ax = fmaf(v.w, wx[3], ax);
                ay = fmaf(v.x, wy[0], ay); ay = fmaf(v.y, wy[1], ay);
                ay = fmaf(v.z, wy[2], ay); ay = fmaf(v.w, wy[3], ay);
            }
        }
    }
    part[((long)0 * 16 + chunk) * totpix + id] = ax;
    part[((long)1 * 16 + chunk) * totpix + id] = ay;
}

// ---------------- k_off_red ----------------
__global__ __launch_bounds__(256) void k_off_red(
    const float* __restrict__ part, const float* __restrict__ avgb, int level,
    float* __restrict__ ox, float* __restrict__ oy, int totpix) {
    int id = blockIdx.x * 256 + threadIdx.x;
    if (id >= totpix) return;
    float sx = avgb[level * 2 + 0], sy = avgb[level * 2 + 1];
    #pragma unroll
    for (int c = 0; c < 16; c++) sx += part[(long)c * totpix + id];
    #pragma unroll
    for (int c = 0; c < 16; c++) sy += part[((long)16 + c) * totpix + id];
    ox[id] = sx; oy[id] = sy;
}

// ---------------- k_snake: desc once, 8 groups/block, double-buffered LDS ----------------
#define GPB 8
__global__ __launch_bounds__(256) void k_snake(
    const float4* __restrict__ tagv,
    const float* __restrict__ ox, const float* __restrict__ oy,
    const float* __restrict__ dww, const float* __restrict__ pww,
    const float* __restrict__ wsc,
    float4* __restrict__ outv, int B, int hh, int ww) {
    __shared__ float s[2][4][18][18];
    __shared__ float4 w4[324];
    __shared__ int4 i4[324];
    __shared__ float dwW[GPB][36];
    __shared__ float pwW[GPB][16];
    __shared__ float wscW[GPB][4];
    int tilesX = ww >> 4;
    int tile = blockIdx.x;
    int g0 = blockIdx.y * GPB;
    int b = blockIdx.z;
    int i0 = (tile / tilesX) * 16;
    int j0 = (tile % tilesX) * 16;
    int tid = threadIdx.x;
    for (int t = tid; t < GPB * 36; t += 256) dwW[t / 36][t % 36] = dww[g0 * 36 + t];
    if (tid < GPB * 16) pwW[tid / 16][tid % 16] = pww[g0 * 16 + tid];
    else if (tid < GPB * 16 + GPB * 4) {
        int r = tid - GPB * 16;
        wscW[r / 4][r % 4] = wsc[g0 * 4 + r];
    }
    int npix = hh * ww;
    const float* oxb = ox + (long)b * npix;
    const float* oyb = oy + (long)b * npix;
    float mW = (float)(ww - 1), mH = (float)(hh - 1);
    // phase A: sample descriptors (shared by all GPB groups)
    for (int p = tid; p < 324; p += 256) {
        int ty = p / 18, tx = p % 18;
        int y = i0 - 1 + ty, x = j0 - 1 + tx;
        float4 wv = make_float4(0.f, 0.f, 0.f, 0.f);
        int4 iv = make_int4(0, 0, 0, 0);
        if ((unsigned)y < (unsigned)hh && (unsigned)x < (unsigned)ww) {
            float px = (float)x + oxb[y * ww + x];
            float py = (float)y + oyb[y * ww + x];
            px = reflectf(px, mW);
            py = reflectf(py, mH);
            float x0f = floorf(px), y0f = floorf(py);
            float fx = px - x0f, fy = py - y0f;
            int x0 = min(max((int)x0f, 0), ww - 1);
            int y0 = min(max((int)y0f, 0), hh - 1);
            int x1 = min(x0 + 1, ww - 1);
            int y1 = min(y0 + 1, hh - 1);
            wv.x = (1.f - fx) * (1.f - fy); wv.y = fx * (1.f - fy);
            wv.z = (1.f - fx) * fy;         wv.w = fx * fy;
            iv.x = y0 * ww + x0; iv.y = y0 * ww + x1;
            iv.z = y1 * ww + x0; iv.w = y1 * ww + x1;
        }
        w4[p] = wv; i4[p] = iv;
    }
    __syncthreads();
    // prefill buffer 0 with group g0
    {
        const float4* pg = tagv + ((long)b * 64 + g0) * npix;
        for (int p = tid; p < 324; p += 256) {
            float4 wv = w4[p]; int4 iv = i4[p];
            float4 v00 = pg[iv.x], v01 = pg[iv.y], v10 = pg[iv.z], v11 = pg[iv.w];
            int ty = p / 18, tx = p % 18;
            s[0][0][ty][tx] = v00.x * wv.x + v01.x * wv.y + v10.x * wv.z + v11.x * wv.w;
            s[0][1][ty][tx] = v00.y * wv.x + v01.y * wv.y + v10.y * wv.z + v11.y * wv.w;
            s[0][2][ty][tx] = v00.z * wv.x + v01.z * wv.y + v10.z * wv.z + v11.z * wv.w;
            s[0][3][ty][tx] = v00.w * wv.x + v01.w * wv.y + v10.w * wv.z + v11.w * wv.w;
        }
    }
    __syncthreads();
    int ti = tid >> 4, tj = tid & 15;
    int oi = i0 + ti, oj = j0 + tj;
    long outbase = ((long)b * 64 + g0) * npix + (long)oi * ww + oj;
    #pragma unroll
    for (int gg = 0; gg < GPB; gg++) {
        int cur = gg & 1;
        // fill next buffer (issues gathers early; overlaps with conv below)
        if (gg + 1 < GPB) {
            const float4* pg = tagv + ((long)b * 64 + g0 + gg + 1) * npix;
            for (int p = tid; p < 324; p += 256) {
                float4 wv = w4[p]; int4 iv = i4[p];
                float4 v00 = pg[iv.x], v01 = pg[iv.y], v10 = pg[iv.z], v11 = pg[iv.w];
                int ty = p / 18, tx = p % 18;
                s[cur ^ 1][0][ty][tx] = v00.x * wv.x + v01.x * wv.y + v10.x * wv.z + v11.x * wv.w;
                s[cur ^ 1][1][ty][tx] = v00.y * wv.x + v01.y * wv.y + v10.y * wv.z + v11.y * wv.w;
                s[cur ^ 1][2][ty][tx] = v00.z * wv.x + v01.z * wv.y + v10.z * wv.z + v11.z * wv.w;
                s[cur ^ 1][3][ty][tx] = v00.w * wv.x + v01.w * wv.y + v10.w * wv.z + v11.w * wv.w;
            }
        }
        // conv from current buffer
        float r[4];
        #pragma unroll
        for (int cc = 0; cc < 4; cc++) {
            float acc = 0.f;
            #pragma unroll
            for (int di = 0; di < 3; di++)
                #pragma unroll
                for (int dj = 0; dj < 3; dj++)
                    acc = fmaf(s[cur][cc][ti + di][tj + dj], dwW[gg][cc * 9 + di * 3 + dj], acc);
            r[cc] = fmaxf(acc, 0.f);
        }
        float4 o;
        o.x = (r[0] * pwW[gg][0]  + r[1] * pwW[gg][1]  + r[2] * pwW[gg][2]  + r[3] * pwW[gg][3])  * wscW[gg][0];
        o.y = (r[0] * pwW[gg][4]  + r[1] * pwW[gg][5]  + r[2] * pwW[gg][6]  + r[3] * pwW[gg][7])  * wscW[gg][1];
        o.z = (r[0] * pwW[gg][8]  + r[1] * pwW[gg][9]  + r[2] * pwW[gg][10] + r[3] * pwW[gg][11]) * wscW[gg][2];
        o.w = (r[0] * pwW[gg][12] + r[1] * pwW[gg][13] + r[2] * pwW[gg][14] + r[3] * pwW[gg][15]) * wscW[gg][3];
        outv[outbase + (long)gg * npix] = o;
        __syncthreads();
    }
}

// ---------------- k_iwt ----------------
__global__ __launch_bounds__(256) void k_iwt(
    const float4* __restrict__ coefv, float* __restrict__ out,
    int B, int hh, int ww) {
    int total = B * 64 * hh * ww;
    int id = blockIdx.x * 256 + threadIdx.x;
    if (id >= total) return;
    int j = id % ww; int t = id / ww;
    int i = t % hh; t /= hh;
    int c = t & 63; int b = t >> 6;
    float4 cf = coefv[id];
    int W2 = ww * 2;
    float* o = out + (((long)(b * 64 + c) * (2 * hh)) + 2 * i) * W2 + 2 * j;
    *(float2*)o        = make_float2(0.5f * (cf.x + cf.y + cf.z + cf.w),
                                     0.5f * (cf.x + cf.y - cf.z - cf.w));
    *(float2*)(o + W2) = make_float2(0.5f * (cf.x - cf.y + cf.z - cf.w),
                                     0.5f * (cf.x - cf.y - cf.z + cf.w));
}

// ---------------- k_final ----------------
__global__ __launch_bounds__(256) void k_final(
    const float4* __restrict__ tagp0v, const float* __restrict__ nxt1,
    const float* __restrict__ x,
    const float* __restrict__ bw, const float* __restrict__ bb,
    const float* __restrict__ bs, float* __restrict__ out) {
    int blk = blockIdx.x;
    int tile = blk & 15; int c = (blk >> 4) & 63; int b = blk >> 10;
    int ty0 = (tile >> 2) * 32, tx0 = (tile & 3) * 32;
    __shared__ float xs[34][36];
    const float* xb = x + (long)(b * 64 + c) * 16384;
    int tid = threadIdx.x;
    for (int p = tid; p < 34 * 34; p += 256) {
        int r = p / 34, q = p % 34;
        int y = ty0 - 1 + r, xg = tx0 - 1 + q;
        float v = 0.f;
        if ((unsigned)y < 128u && (unsigned)xg < 128u) v = xb[y * 128 + xg];
        xs[r][q] = v;
    }
    float w0 = bw[c * 9 + 0], w1 = bw[c * 9 + 1], w2 = bw[c * 9 + 2];
    float w3 = bw[c * 9 + 3], w4 = bw[c * 9 + 4], w5 = bw[c * 9 + 5];
    float w6 = bw[c * 9 + 6], w7 = bw[c * 9 + 7], w8 = bw[c * 9 + 8];
    float bias = bb[c], scale = bs[c];
    __syncthreads();
    int ti = tid >> 4, tj = tid & 15;
    int yy = ty0 + 2 * ti, xx = tx0 + 2 * tj;
    int i = yy >> 1, j = xx >> 1;
    long cidx = (((long)(b * 64 + c) * 64) + i) * 64 + j;
    float4 cf = tagp0v[cidx];
    float c0 = cf.x + nxt1[cidx];
    float c1 = cf.y, c2 = cf.z, c3 = cf.w;
    float rec00 = 0.5f * (c0 + c1 + c2 + c3);
    float rec01 = 0.5f * (c0 + c1 - c2 - c3);
    float rec10 = 0.5f * (c0 - c1 + c2 - c3);
    float rec11 = 0.5f * (c0 - c1 - c2 + c3);
    float o00, o01, o10, o11;
    {
        int a = 2 * ti, bq = 2 * tj;
        #define CONV(dy,dx) ({ \
            float acc = bias; \
            acc = fmaf(xs[a+dy+0][bq+dx+0], w0, acc); \
            acc = fmaf(xs[a+dy+0][bq+dx+1], w1, acc); \
            acc = fmaf(xs[a+dy+0][bq+dx+2], w2, acc); \
            acc = fmaf(xs[a+dy+1][bq+dx+0], w3, acc); \
            acc = fmaf(xs[a+dy+1][bq+dx+1], w4, acc); \
            acc = fmaf(xs[a+dy+1][bq+dx+2], w5, acc); \
            acc = fmaf(xs[a+dy+2][bq+dx+0], w6, acc); \
            acc = fmaf(xs[a+dy+2][bq+dx+1], w7, acc); \
            acc = fmaf(xs[a+dy+2][bq+dx+2], w8, acc); \
            acc; })
        o00 = scale * CONV(0,0) + rec00;
        o01 = scale * CONV(0,1) + rec01;
        o10 = scale * CONV(1,0) + rec10;
        o11 = scale * CONV(1,1) + rec11;
        #undef CONV
    }
    float* ob = out + (((long)(b * 64 + c) * 128) + yy) * 128 + xx;
    *(float2*)ob         = make_float2(o00, o01);
    *(float2*)(ob + 128) = make_float2(o10, o11);
}

// ---------------- launch ----------------
extern "C" void kernel_launch(void* const* d_in, const int* in_sizes, int n_in,
                              void* d_out, int out_size, void* d_ws, size_t ws_size,
                              hipStream_t stream) {
    const float* x     = (const float*)d_in[0];
    const float* bw    = (const float*)d_in[1];
    const float* bb    = (const float*)d_in[2];
    const float* bs    = (const float*)d_in[3];
    const float* offw0 = (const float*)d_in[4];
    const float* offb0 = (const float*)d_in[5];
    const float* dww0  = (const float*)d_in[6];
    const float* pww0  = (const float*)d_in[7];
    const float* wsc0  = (const float*)d_in[8];
    const float* offw1 = (const float*)d_in[9];
    const float* offb1 = (const float*)d_in[10];
    const float* dww1  = (const float*)d_in[11];
    const float* pww1  = (const float*)d_in[12];
    const float* wsc1  = (const float*)d_in[13];
    float* out = (float*)d_out;
    float* ws = (float*)d_ws;

    float* tag0  = ws + 0L;
    float* tag1  = ws + 16777216L;
    float* tagp1 = ws + 20971520L;
    float* tagp0 = ws + 25165824L;
    float* avgw  = ws + 41943040L;
    float* avgb  = ws + 41952256L;
    float* ox0   = ws + 41952260L;
    float* oy0   = ws + 42017796L;
    float* ox1   = ws + 42083332L;
    float* oy1   = ws + 42099716L;
    float* nxt1  = tag1;
    float* part1 = tagp1;
    float* part0 = tagp0;

    k_prep<<<36, 256, 0, stream>>>(offw0, offb0, offw1, offb1, avgw, avgb);
    k_wt0<<<16384, 256, 0, stream>>>(x, (float4*)tag0);
    k_wt1<<<4096, 256, 0, stream>>>(tag0, (float4*)tag1);
    k_off_part<<<dim3(64, 16), 256, 0, stream>>>((const float4*)tag1, avgw, 1, part1, 16, 32, 32);
    k_off_red<<<64, 256, 0, stream>>>(part1, avgb, 1, ox1, oy1, 16384);
    k_snake<<<dim3(4, 8, 16), 256, 0, stream>>>((const float4*)tag1, ox1, oy1, dww1, pww1, wsc1,
                                                (float4*)tagp1, 16, 32, 32);
    k_iwt<<<4096, 256, 0, stream>>>((const float4*)tagp1, nxt1, 16, 32, 32);
    k_off_part<<<dim3(256, 16), 256, 0, stream>>>((const float4*)tag0, avgw, 0, part0, 16, 64, 64);
    k_off_red<<<256, 256, 0, stream>>>(part0, avgb, 0, ox0, oy0, 65536);
    k_snake<<<dim3(16, 8, 16), 256, 0, stream>>>((const float4*)tag0, ox0, oy0, dww0, pww0, wsc0,
                                                 (float4*)tagp0, 16, 64, 64);
    k_final<<<16384, 256, 0, stream>>>((const float4*)tagp0, nxt1, x, bw, bb, bs, out);
}

// Round 5
// 201.200 us; speedup vs baseline: 4.5417x; 1.1462x over previous
//
#include <hip/hip_runtime.h>

// ---------------- helpers ----------------
static __device__ __forceinline__ float reflectf(float coord, float m) {
    float period = 2.0f * m;
    float c = fmodf(fabsf(coord), period);
    c = (c > m) ? (period - c) : c;
    return fminf(fmaxf(c, 0.0f), m);
}

// ---------------- k_prep ----------------
__global__ __launch_bounds__(256) void k_prep(
    const float* __restrict__ offw0, const float* __restrict__ offb0,
    const float* __restrict__ offw1, const float* __restrict__ offb1,
    float* __restrict__ avgw, float* __restrict__ avgb) {
    int id = blockIdx.x * blockDim.x + threadIdx.x;
    if (id < 2 * 2 * 2304) {
        int l = id / 4608;
        int rem = id % 4608;
        int d = rem / 2304;
        int r = rem % 2304;
        const float* w = l ? offw1 : offw0;
        float s = w[(d * 3 + 0) * 2304 + r] + w[(d * 3 + 1) * 2304 + r] + w[(d * 3 + 2) * 2304 + r];
        avgw[id] = s * (1.0f / 3.0f);
    }
    if (id == 0) {
        avgb[0] = (offb0[0] + offb0[1] + offb0[2]) * (1.0f / 3.0f);
        avgb[1] = (offb0[3] + offb0[4] + offb0[5]) * (1.0f / 3.0f);
        avgb[2] = (offb1[0] + offb1[1] + offb1[2]) * (1.0f / 3.0f);
        avgb[3] = (offb1[3] + offb1[4] + offb1[5]) * (1.0f / 3.0f);
    }
}

// ---------------- k_wt01: fused level-0 + level-1 Haar DWT ----------------
// one thread = 4x4 x-patch -> 4 tag0 vec4 + 1 tag1 vec4
__global__ __launch_bounds__(256) void k_wt01(
    const float* __restrict__ x, float4* __restrict__ tag0v, float4* __restrict__ tag1v) {
    int id = blockIdx.x * 256 + threadIdx.x;
    if (id >= 16 * 64 * 32 * 32) return;
    int j1 = id & 31; int t = id >> 5;
    int i1 = t & 31; t >>= 5;
    int c = t & 63; int b = t >> 6;
    const float* p = x + ((long)(b * 64 + c) * 128 + 4 * i1) * 128 + 4 * j1;
    float4 r0 = *(const float4*)p;
    float4 r1 = *(const float4*)(p + 128);
    float4 r2 = *(const float4*)(p + 256);
    float4 r3 = *(const float4*)(p + 384);
    #define HAAR(a0,a1,a2,a3) make_float4(0.5f*((a0)+(a1)+(a2)+(a3)), 0.5f*((a0)+(a1)-(a2)-(a3)), \
                                          0.5f*((a0)-(a1)+(a2)-(a3)), 0.5f*((a0)-(a1)-(a2)+(a3)))
    float4 t00 = HAAR(r0.x, r0.y, r1.x, r1.y);
    float4 t01 = HAAR(r0.z, r0.w, r1.z, r1.w);
    float4 t10 = HAAR(r2.x, r2.y, r3.x, r3.y);
    float4 t11 = HAAR(r2.z, r2.w, r3.z, r3.w);
    long pbase = (long)(b * 64 + c) * 4096;
    int i0 = 2 * i1, j0 = 2 * j1;
    tag0v[pbase + (long)i0 * 64 + j0]           = t00;
    tag0v[pbase + (long)i0 * 64 + j0 + 1]       = t01;
    tag0v[pbase + (long)(i0 + 1) * 64 + j0]     = t10;
    tag0v[pbase + (long)(i0 + 1) * 64 + j0 + 1] = t11;
    tag1v[(long)(b * 64 + c) * 1024 + (long)i1 * 32 + j1] = HAAR(t00.x, t01.x, t10.x, t11.x);
    #undef HAAR
}

// ---------------- k_off_part (numerically untouched) ----------------
__global__ __launch_bounds__(256) void k_off_part(
    const float4* __restrict__ tagv, const float* __restrict__ avgw, int level,
    float* __restrict__ part, int B, int hh, int ww) {
    int chunk = blockIdx.y;
    int npix = hh * ww;
    int totpix = B * npix;
    __shared__ float wls[2][4][9][4];
    const float* wsrc = avgw + level * 4608;
    int tid = threadIdx.x;
    if (tid < 288) {
        int d = tid / 144, rem = tid % 144;
        int gg = rem / 36; int tap = (rem % 36) / 4; int cc = tid & 3;
        wls[d][gg][tap][cc] = wsrc[d * 2304 + (chunk * 16 + gg * 4 + cc) * 9 + tap];
    }
    __syncthreads();
    int id = blockIdx.x * 256 + tid;
    if (id >= totpix) return;
    int j = id % ww; int t = id / ww;
    int i = t % hh; int b = t / hh;
    float ax = 0.f, ay = 0.f;
    #pragma unroll
    for (int gg = 0; gg < 4; gg++) {
        const float4* pg = tagv + ((long)b * 64 + chunk * 4 + gg) * npix;
        #pragma unroll
        for (int di = 0; di < 3; di++) {
            int y = i + di - 1;
            if ((unsigned)y >= (unsigned)hh) continue;
            #pragma unroll
            for (int dj = 0; dj < 3; dj++) {
                int x = j + dj - 1;
                if ((unsigned)x >= (unsigned)ww) continue;
                float4 v = pg[y * ww + x];
                const float* wx = &wls[0][gg][di * 3 + dj][0];
                const float* wy = &wls[1][gg][di * 3 + dj][0];
                ax = fmaf(v.x, wx[0], ax); ax = fmaf(v.y, wx[1], ax);
                ax = fmaf(v.z, wx[2], ax); ax = fmaf(v.w, wx[3], ax);
                ay = fmaf(v.x, wy[0], ay); ay = fmaf(v.y, wy[1], ay);
                ay = fmaf(v.z, wy[2], ay); ay = fmaf(v.w, wy[3], ay);
            }
        }
    }
    part[((long)0 * 16 + chunk) * totpix + id] = ax;
    part[((long)1 * 16 + chunk) * totpix + id] = ay;
}

// ---------------- k_off_red ----------------
__global__ __launch_bounds__(256) void k_off_red(
    const float* __restrict__ part, const float* __restrict__ avgb, int level,
    float* __restrict__ ox, float* __restrict__ oy, int totpix) {
    int id = blockIdx.x * 256 + threadIdx.x;
    if (id >= totpix) return;
    float sx = avgb[level * 2 + 0], sy = avgb[level * 2 + 1];
    #pragma unroll
    for (int c = 0; c < 16; c++) sx += part[(long)c * totpix + id];
    #pragma unroll
    for (int c = 0; c < 16; c++) sy += part[((long)16 + c) * totpix + id];
    ox[id] = sx; oy[id] = sy;
}

// ---------------- k_snake: reg-prefetched pipeline over GPB groups ----------------
template<int GPB>
__global__ __launch_bounds__(256) void k_snake(
    const float4* __restrict__ tagv,
    const float* __restrict__ ox, const float* __restrict__ oy,
    const float* __restrict__ dww, const float* __restrict__ pww,
    const float* __restrict__ wsc,
    float4* __restrict__ outv, int B, int hh, int ww) {
    __shared__ float4 sbuf[2][18][18];
    __shared__ float dwW[GPB][36];
    __shared__ float pwW[GPB][16];
    __shared__ float wscW[GPB][4];
    int tilesX = ww >> 4;
    int tile = blockIdx.x;
    int g0 = blockIdx.y * GPB;
    int bz = blockIdx.z;
    int i0 = (tile / tilesX) * 16;
    int j0 = (tile % tilesX) * 16;
    int tid = threadIdx.x;
    for (int t = tid; t < GPB * 36; t += 256) dwW[t / 36][t % 36] = dww[g0 * 36 + t];
    for (int t = tid; t < GPB * 16; t += 256) pwW[t / 16][t % 16] = pww[g0 * 16 + t];
    for (int t = tid; t < GPB * 4;  t += 256) wscW[t / 4][t % 4]  = wsc[g0 * 4 + t];
    int npix = hh * ww;
    const float* oxb = ox + (long)bz * npix;
    const float* oyb = oy + (long)bz * npix;
    float mW = (float)(ww - 1), mH = (float)(hh - 1);
    // per-thread sample descriptors (p0 = tid, p1 = tid+256 if < 324)
    int p0 = tid, p1 = tid + 256;
    bool has1 = (p1 < 324);
    int ty0 = p0 / 18, tx0 = p0 % 18;
    int ty1 = p1 / 18, tx1 = p1 % 18;
    float4 wv0 = make_float4(0.f, 0.f, 0.f, 0.f), wv1 = wv0;
    int4 iv0 = make_int4(0, 0, 0, 0), iv1 = iv0;
    {
        int y = i0 - 1 + ty0, x = j0 - 1 + tx0;
        if (p0 < 324 && (unsigned)y < (unsigned)hh && (unsigned)x < (unsigned)ww) {
            float px = (float)x + oxb[y * ww + x];
            float py = (float)y + oyb[y * ww + x];
            px = reflectf(px, mW); py = reflectf(py, mH);
            float x0f = floorf(px), y0f = floorf(py);
            float fx = px - x0f, fy = py - y0f;
            int x0 = min(max((int)x0f, 0), ww - 1);
            int y0 = min(max((int)y0f, 0), hh - 1);
            int x1 = min(x0 + 1, ww - 1);
            int y1 = min(y0 + 1, hh - 1);
            wv0.x = (1.f - fx) * (1.f - fy); wv0.y = fx * (1.f - fy);
            wv0.z = (1.f - fx) * fy;         wv0.w = fx * fy;
            iv0.x = y0 * ww + x0; iv0.y = y0 * ww + x1;
            iv0.z = y1 * ww + x0; iv0.w = y1 * ww + x1;
        }
        y = i0 - 1 + ty1; x = j0 - 1 + tx1;
        if (has1 && (unsigned)y < (unsigned)hh && (unsigned)x < (unsigned)ww) {
            float px = (float)x + oxb[y * ww + x];
            float py = (float)y + oyb[y * ww + x];
            px = reflectf(px, mW); py = reflectf(py, mH);
            float x0f = floorf(px), y0f = floorf(py);
            float fx = px - x0f, fy = py - y0f;
            int x0 = min(max((int)x0f, 0), ww - 1);
            int y0 = min(max((int)y0f, 0), hh - 1);
            int x1 = min(x0 + 1, ww - 1);
            int y1 = min(y0 + 1, hh - 1);
            wv1.x = (1.f - fx) * (1.f - fy); wv1.y = fx * (1.f - fy);
            wv1.z = (1.f - fx) * fy;         wv1.w = fx * fy;
            iv1.x = y0 * ww + x0; iv1.y = y0 * ww + x1;
            iv1.z = y1 * ww + x0; iv1.w = y1 * ww + x1;
        }
    }
    float4 a00, a01, a10, a11, b00, b01, b10, b11;
    #define ISSUE(g) { const float4* pg = tagv + ((long)bz * 64 + (g)) * npix; \
        a00 = pg[iv0.x]; a01 = pg[iv0.y]; a10 = pg[iv0.z]; a11 = pg[iv0.w]; \
        if (has1) { b00 = pg[iv1.x]; b01 = pg[iv1.y]; b10 = pg[iv1.z]; b11 = pg[iv1.w]; } }
    #define WRITEBUF(nb) { \
        sbuf[nb][ty0][tx0] = make_float4( \
            a00.x * wv0.x + a01.x * wv0.y + a10.x * wv0.z + a11.x * wv0.w, \
            a00.y * wv0.x + a01.y * wv0.y + a10.y * wv0.z + a11.y * wv0.w, \
            a00.z * wv0.x + a01.z * wv0.y + a10.z * wv0.z + a11.z * wv0.w, \
            a00.w * wv0.x + a01.w * wv0.y + a10.w * wv0.z + a11.w * wv0.w); \
        if (has1) sbuf[nb][ty1][tx1] = make_float4( \
            b00.x * wv1.x + b01.x * wv1.y + b10.x * wv1.z + b11.x * wv1.w, \
            b00.y * wv1.x + b01.y * wv1.y + b10.y * wv1.z + b11.y * wv1.w, \
            b00.z * wv1.x + b01.z * wv1.y + b10.z * wv1.z + b11.z * wv1.w, \
            b00.w * wv1.x + b01.w * wv1.y + b10.w * wv1.z + b11.w * wv1.w); }
    ISSUE(g0);
    WRITEBUF(0);
    __syncthreads();
    int ti = tid >> 4, tj = tid & 15;
    int oi = i0 + ti, oj = j0 + tj;
    long outbase = ((long)bz * 64 + g0) * npix + (long)oi * ww + oj;
    #pragma unroll
    for (int gg = 0; gg < GPB; gg++) {
        const int cur = gg & 1;
        if (gg + 1 < GPB) ISSUE(g0 + gg + 1);
        // conv from sbuf[cur]
        float4 acc = make_float4(0.f, 0.f, 0.f, 0.f);
        #pragma unroll
        for (int di = 0; di < 3; di++)
            #pragma unroll
            for (int dj = 0; dj < 3; dj++) {
                float4 v = sbuf[cur][ti + di][tj + dj];
                int tap = di * 3 + dj;
                acc.x = fmaf(v.x, dwW[gg][0 * 9 + tap], acc.x);
                acc.y = fmaf(v.y, dwW[gg][1 * 9 + tap], acc.y);
                acc.z = fmaf(v.z, dwW[gg][2 * 9 + tap], acc.z);
                acc.w = fmaf(v.w, dwW[gg][3 * 9 + tap], acc.w);
            }
        float r0 = fmaxf(acc.x, 0.f), r1 = fmaxf(acc.y, 0.f);
        float r2 = fmaxf(acc.z, 0.f), r3 = fmaxf(acc.w, 0.f);
        float4 o;
        o.x = (r0 * pwW[gg][0]  + r1 * pwW[gg][1]  + r2 * pwW[gg][2]  + r3 * pwW[gg][3])  * wscW[gg][0];
        o.y = (r0 * pwW[gg][4]  + r1 * pwW[gg][5]  + r2 * pwW[gg][6]  + r3 * pwW[gg][7])  * wscW[gg][1];
        o.z = (r0 * pwW[gg][8]  + r1 * pwW[gg][9]  + r2 * pwW[gg][10] + r3 * pwW[gg][11]) * wscW[gg][2];
        o.w = (r0 * pwW[gg][12] + r1 * pwW[gg][13] + r2 * pwW[gg][14] + r3 * pwW[gg][15]) * wscW[gg][3];
        outv[outbase + (long)gg * npix] = o;
        if (gg + 1 < GPB) {
            WRITEBUF(cur ^ 1);
            __syncthreads();
        }
    }
    #undef ISSUE
    #undef WRITEBUF
}

// ---------------- k_final: inline level-1 iwt + level-0 iwt + base dw conv ----------------
__global__ __launch_bounds__(256) void k_final(
    const float4* __restrict__ tagp0v, const float4* __restrict__ tagp1v,
    const float* __restrict__ x,
    const float* __restrict__ bw, const float* __restrict__ bb,
    const float* __restrict__ bs, float* __restrict__ out) {
    int blk = blockIdx.x;
    int tile = blk & 15; int c = (blk >> 4) & 63; int b = blk >> 10;
    int ty0 = (tile >> 2) * 32, tx0 = (tile & 3) * 32;
    __shared__ float xs[34][36];
    const float* xb = x + (long)(b * 64 + c) * 16384;
    int tid = threadIdx.x;
    for (int p = tid; p < 34 * 34; p += 256) {
        int r = p / 34, q = p % 34;
        int y = ty0 - 1 + r, xg = tx0 - 1 + q;
        float v = 0.f;
        if ((unsigned)y < 128u && (unsigned)xg < 128u) v = xb[y * 128 + xg];
        xs[r][q] = v;
    }
    float w0 = bw[c * 9 + 0], w1 = bw[c * 9 + 1], w2 = bw[c * 9 + 2];
    float w3 = bw[c * 9 + 3], w4 = bw[c * 9 + 4], w5 = bw[c * 9 + 5];
    float w6 = bw[c * 9 + 6], w7 = bw[c * 9 + 7], w8 = bw[c * 9 + 8];
    float bias = bb[c], scale = bs[c];
    __syncthreads();
    int ti = tid >> 4, tj = tid & 15;
    int yy = ty0 + 2 * ti, xx = tx0 + 2 * tj;
    int i = yy >> 1, j = xx >> 1;
    long cidx = (((long)(b * 64 + c) * 64) + i) * 64 + j;
    float4 cf = tagp0v[cidx];
    // inline level-1 inverse Haar (bit-identical to former k_iwt + load)
    float4 d = tagp1v[((long)(b * 64 + c) * 1024) + (long)(i >> 1) * 32 + (j >> 1)];
    float sr = (i & 1) ? -1.f : 1.f;
    float sc = (j & 1) ? -1.f : 1.f;
    float nv = 0.5f * (d.x + sr * d.y + sc * d.z + sr * sc * d.w);
    float c0 = cf.x + nv;
    float c1 = cf.y, c2 = cf.z, c3 = cf.w;
    float rec00 = 0.5f * (c0 + c1 + c2 + c3);
    float rec01 = 0.5f * (c0 + c1 - c2 - c3);
    float rec10 = 0.5f * (c0 - c1 + c2 - c3);
    float rec11 = 0.5f * (c0 - c1 - c2 + c3);
    float o00, o01, o10, o11;
    {
        int a = 2 * ti, bq = 2 * tj;
        #define CONV(dy,dx) ({ \
            float acc = bias; \
            acc = fmaf(xs[a+dy+0][bq+dx+0], w0, acc); \
            acc = fmaf(xs[a+dy+0][bq+dx+1], w1, acc); \
            acc = fmaf(xs[a+dy+0][bq+dx+2], w2, acc); \
            acc = fmaf(xs[a+dy+1][bq+dx+0], w3, acc); \
            acc = fmaf(xs[a+dy+1][bq+dx+1], w4, acc); \
            acc = fmaf(xs[a+dy+1][bq+dx+2], w5, acc); \
            acc = fmaf(xs[a+dy+2][bq+dx+0], w6, acc); \
            acc = fmaf(xs[a+dy+2][bq+dx+1], w7, acc); \
            acc = fmaf(xs[a+dy+2][bq+dx+2], w8, acc); \
            acc; })
        o00 = scale * CONV(0,0) + rec00;
        o01 = scale * CONV(0,1) + rec01;
        o10 = scale * CONV(1,0) + rec10;
        o11 = scale * CONV(1,1) + rec11;
        #undef CONV
    }
    float* ob = out + (((long)(b * 64 + c) * 128) + yy) * 128 + xx;
    *(float2*)ob         = make_float2(o00, o01);
    *(float2*)(ob + 128) = make_float2(o10, o11);
}

// ---------------- launch ----------------
extern "C" void kernel_launch(void* const* d_in, const int* in_sizes, int n_in,
                              void* d_out, int out_size, void* d_ws, size_t ws_size,
                              hipStream_t stream) {
    const float* x     = (const float*)d_in[0];
    const float* bw    = (const float*)d_in[1];
    const float* bb    = (const float*)d_in[2];
    const float* bs    = (const float*)d_in[3];
    const float* offw0 = (const float*)d_in[4];
    const float* offb0 = (const float*)d_in[5];
    const float* dww0  = (const float*)d_in[6];
    const float* pww0  = (const float*)d_in[7];
    const float* wsc0  = (const float*)d_in[8];
    const float* offw1 = (const float*)d_in[9];
    const float* offb1 = (const float*)d_in[10];
    const float* dww1  = (const float*)d_in[11];
    const float* pww1  = (const float*)d_in[12];
    const float* wsc1  = (const float*)d_in[13];
    float* out = (float*)d_out;
    float* ws = (float*)d_ws;

    float* tag0  = ws + 0L;
    float* tag1  = ws + 16777216L;
    float* tagp1 = ws + 20971520L;
    float* tagp0 = ws + 25165824L;
    float* avgw  = ws + 41943040L;
    float* avgb  = ws + 41952256L;
    float* ox0   = ws + 41952260L;
    float* oy0   = ws + 42017796L;
    float* ox1   = ws + 42083332L;
    float* oy1   = ws + 42099716L;
    float* part1 = tagp1;   // consumed before k_snake1 writes tagp1
    float* part0 = tagp0;   // consumed before k_snake0 writes tagp0

    k_prep<<<36, 256, 0, stream>>>(offw0, offb0, offw1, offb1, avgw, avgb);
    // fused DWT levels 0+1
    k_wt01<<<4096, 256, 0, stream>>>(x, (float4*)tag0, (float4*)tag1);
    // level-1 offsets
    k_off_part<<<dim3(64, 16), 256, 0, stream>>>((const float4*)tag1, avgw, 1, part1, 16, 32, 32);
    k_off_red<<<64, 256, 0, stream>>>(part1, avgb, 1, ox1, oy1, 16384);
    // level-1 snake -> tagp1
    k_snake<4><<<dim3(4, 16, 16), 256, 0, stream>>>((const float4*)tag1, ox1, oy1, dww1, pww1, wsc1,
                                                    (float4*)tagp1, 16, 32, 32);
    // level-0 offsets
    k_off_part<<<dim3(256, 16), 256, 0, stream>>>((const float4*)tag0, avgw, 0, part0, 16, 64, 64);
    k_off_red<<<256, 256, 0, stream>>>(part0, avgb, 0, ox0, oy0, 65536);
    // level-0 snake -> tagp0
    k_snake<8><<<dim3(16, 8, 16), 256, 0, stream>>>((const float4*)tag0, ox0, oy0, dww0, pww0, wsc0,
                                                    (float4*)tagp0, 16, 64, 64);
    // final: inline iwt(level1) + iwt(level0) + base conv
    k_final<<<16384, 256, 0, stream>>>((const float4*)tagp0, (const float4*)tagp1, x, bw, bb, bs, out);
}

// Round 6
// 177.689 us; speedup vs baseline: 5.1426x; 1.1323x over previous
//
#include <hip/hip_runtime.h>

// ---------------- helpers ----------------
static __device__ __forceinline__ float reflectf(float coord, float m) {
    float period = 2.0f * m;
    float c = fmodf(fabsf(coord), period);
    c = (c > m) ? (period - c) : c;
    return fminf(fmaxf(c, 0.0f), m);
}

// ---------------- k_prep ----------------
__global__ __launch_bounds__(256) void k_prep(
    const float* __restrict__ offw0, const float* __restrict__ offb0,
    const float* __restrict__ offw1, const float* __restrict__ offb1,
    float* __restrict__ avgw, float* __restrict__ avgb) {
    int id = blockIdx.x * blockDim.x + threadIdx.x;
    if (id < 2 * 2 * 2304) {
        int l = id / 4608;
        int rem = id % 4608;
        int d = rem / 2304;
        int r = rem % 2304;
        const float* w = l ? offw1 : offw0;
        float s = w[(d * 3 + 0) * 2304 + r] + w[(d * 3 + 1) * 2304 + r] + w[(d * 3 + 2) * 2304 + r];
        avgw[id] = s * (1.0f / 3.0f);
    }
    if (id == 0) {
        avgb[0] = (offb0[0] + offb0[1] + offb0[2]) * (1.0f / 3.0f);
        avgb[1] = (offb0[3] + offb0[4] + offb0[5]) * (1.0f / 3.0f);
        avgb[2] = (offb1[0] + offb1[1] + offb1[2]) * (1.0f / 3.0f);
        avgb[3] = (offb1[3] + offb1[4] + offb1[5]) * (1.0f / 3.0f);
    }
}

// ---------------- k_wt01: fused level-0 + level-1 Haar DWT ----------------
__global__ __launch_bounds__(256) void k_wt01(
    const float* __restrict__ x, float4* __restrict__ tag0v, float4* __restrict__ tag1v) {
    int id = blockIdx.x * 256 + threadIdx.x;
    if (id >= 16 * 64 * 32 * 32) return;
    int j1 = id & 31; int t = id >> 5;
    int i1 = t & 31; t >>= 5;
    int c = t & 63; int b = t >> 6;
    const float* p = x + ((long)(b * 64 + c) * 128 + 4 * i1) * 128 + 4 * j1;
    float4 r0 = *(const float4*)p;
    float4 r1 = *(const float4*)(p + 128);
    float4 r2 = *(const float4*)(p + 256);
    float4 r3 = *(const float4*)(p + 384);
    #define HAAR(a0,a1,a2,a3) make_float4(0.5f*((a0)+(a1)+(a2)+(a3)), 0.5f*((a0)+(a1)-(a2)-(a3)), \
                                          0.5f*((a0)-(a1)+(a2)-(a3)), 0.5f*((a0)-(a1)-(a2)+(a3)))
    float4 t00 = HAAR(r0.x, r0.y, r1.x, r1.y);
    float4 t01 = HAAR(r0.z, r0.w, r1.z, r1.w);
    float4 t10 = HAAR(r2.x, r2.y, r3.x, r3.y);
    float4 t11 = HAAR(r2.z, r2.w, r3.z, r3.w);
    long pbase = (long)(b * 64 + c) * 4096;
    int i0 = 2 * i1, j0 = 2 * j1;
    tag0v[pbase + (long)i0 * 64 + j0]           = t00;
    tag0v[pbase + (long)i0 * 64 + j0 + 1]       = t01;
    tag0v[pbase + (long)(i0 + 1) * 64 + j0]     = t10;
    tag0v[pbase + (long)(i0 + 1) * 64 + j0 + 1] = t11;
    tag1v[(long)(b * 64 + c) * 1024 + (long)i1 * 32 + j1] = HAAR(t00.x, t01.x, t10.x, t11.x);
    #undef HAAR
}

// ---------------- k_off_part ----------------
__global__ __launch_bounds__(256) void k_off_part(
    const float4* __restrict__ tagv, const float* __restrict__ avgw, int level,
    float* __restrict__ part, int B, int hh, int ww) {
    int chunk = blockIdx.y;
    int npix = hh * ww;
    int totpix = B * npix;
    __shared__ float wls[2][4][9][4];
    const float* wsrc = avgw + level * 4608;
    int tid = threadIdx.x;
    if (tid < 288) {
        int d = tid / 144, rem = tid % 144;
        int gg = rem / 36; int tap = (rem % 36) / 4; int cc = tid & 3;
        wls[d][gg][tap][cc] = wsrc[d * 2304 + (chunk * 16 + gg * 4 + cc) * 9 + tap];
    }
    __syncthreads();
    int id = blockIdx.x * 256 + tid;
    if (id >= totpix) return;
    int j = id % ww; int t = id / ww;
    int i = t % hh; int b = t / hh;
    float ax = 0.f, ay = 0.f;
    #pragma unroll
    for (int gg = 0; gg < 4; gg++) {
        const float4* pg = tagv + ((long)b * 64 + chunk * 4 + gg) * npix;
        #pragma unroll
        for (int di = 0; di < 3; di++) {
            int y = i + di - 1;
            if ((unsigned)y >= (unsigned)hh) continue;
            #pragma unroll
            for (int dj = 0; dj < 3; dj++) {
                int x = j + dj - 1;
                if ((unsigned)x >= (unsigned)ww) continue;
                float4 v = pg[y * ww + x];
                const float* wx = &wls[0][gg][di * 3 + dj][0];
                const float* wy = &wls[1][gg][di * 3 + dj][0];
                ax = fmaf(v.x, wx[0], ax); ax = fmaf(v.y, wx[1], ax);
                ax = fmaf(v.z, wx[2], ax); ax = fmaf(v.w, wx[3], ax);
                ay = fmaf(v.x, wy[0], ay); ay = fmaf(v.y, wy[1], ay);
                ay = fmaf(v.z, wy[2], ay); ay = fmaf(v.w, wy[3], ay);
            }
        }
    }
    part[((long)0 * 16 + chunk) * totpix + id] = ax;
    part[((long)1 * 16 + chunk) * totpix + id] = ay;
}

// ---------------- k_off_red ----------------
__global__ __launch_bounds__(256) void k_off_red(
    const float* __restrict__ part, const float* __restrict__ avgb, int level,
    float* __restrict__ ox, float* __restrict__ oy, int totpix) {
    int id = blockIdx.x * 256 + threadIdx.x;
    if (id >= totpix) return;
    float sx = avgb[level * 2 + 0], sy = avgb[level * 2 + 1];
    #pragma unroll
    for (int c = 0; c < 16; c++) sx += part[(long)c * totpix + id];
    #pragma unroll
    for (int c = 0; c < 16; c++) sy += part[((long)16 + c) * totpix + id];
    ox[id] = sx; oy[id] = sy;
}

// ---------------- k_snake (level 1 only now) ----------------
template<int GPB>
__global__ __launch_bounds__(256) void k_snake(
    const float4* __restrict__ tagv,
    const float* __restrict__ ox, const float* __restrict__ oy,
    const float* __restrict__ dww, const float* __restrict__ pww,
    const float* __restrict__ wsc,
    float4* __restrict__ outv, int B, int hh, int ww) {
    __shared__ float4 sbuf[2][18][18];
    __shared__ float dwW[GPB][36];
    __shared__ float pwW[GPB][16];
    __shared__ float wscW[GPB][4];
    int tilesX = ww >> 4;
    int tile = blockIdx.x;
    int g0 = blockIdx.y * GPB;
    int bz = blockIdx.z;
    int i0 = (tile / tilesX) * 16;
    int j0 = (tile % tilesX) * 16;
    int tid = threadIdx.x;
    for (int t = tid; t < GPB * 36; t += 256) dwW[t / 36][t % 36] = dww[g0 * 36 + t];
    for (int t = tid; t < GPB * 16; t += 256) pwW[t / 16][t % 16] = pww[g0 * 16 + t];
    for (int t = tid; t < GPB * 4;  t += 256) wscW[t / 4][t % 4]  = wsc[g0 * 4 + t];
    int npix = hh * ww;
    const float* oxb = ox + (long)bz * npix;
    const float* oyb = oy + (long)bz * npix;
    float mW = (float)(ww - 1), mH = (float)(hh - 1);
    int p0 = tid, p1 = tid + 256;
    bool has1 = (p1 < 324);
    int ty0 = p0 / 18, tx0 = p0 % 18;
    int ty1 = p1 / 18, tx1 = p1 % 18;
    float4 wv0 = make_float4(0.f, 0.f, 0.f, 0.f), wv1 = wv0;
    int4 iv0 = make_int4(0, 0, 0, 0), iv1 = iv0;
    {
        int y = i0 - 1 + ty0, x = j0 - 1 + tx0;
        if (p0 < 324 && (unsigned)y < (unsigned)hh && (unsigned)x < (unsigned)ww) {
            float px = (float)x + oxb[y * ww + x];
            float py = (float)y + oyb[y * ww + x];
            px = reflectf(px, mW); py = reflectf(py, mH);
            float x0f = floorf(px), y0f = floorf(py);
            float fx = px - x0f, fy = py - y0f;
            int x0 = min(max((int)x0f, 0), ww - 1);
            int y0 = min(max((int)y0f, 0), hh - 1);
            int x1 = min(x0 + 1, ww - 1);
            int y1 = min(y0 + 1, hh - 1);
            wv0.x = (1.f - fx) * (1.f - fy); wv0.y = fx * (1.f - fy);
            wv0.z = (1.f - fx) * fy;         wv0.w = fx * fy;
            iv0.x = y0 * ww + x0; iv0.y = y0 * ww + x1;
            iv0.z = y1 * ww + x0; iv0.w = y1 * ww + x1;
        }
        y = i0 - 1 + ty1; x = j0 - 1 + tx1;
        if (has1 && (unsigned)y < (unsigned)hh && (unsigned)x < (unsigned)ww) {
            float px = (float)x + oxb[y * ww + x];
            float py = (float)y + oyb[y * ww + x];
            px = reflectf(px, mW); py = reflectf(py, mH);
            float x0f = floorf(px), y0f = floorf(py);
            float fx = px - x0f, fy = py - y0f;
            int x0 = min(max((int)x0f, 0), ww - 1);
            int y0 = min(max((int)y0f, 0), hh - 1);
            int x1 = min(x0 + 1, ww - 1);
            int y1 = min(y0 + 1, hh - 1);
            wv1.x = (1.f - fx) * (1.f - fy); wv1.y = fx * (1.f - fy);
            wv1.z = (1.f - fx) * fy;         wv1.w = fx * fy;
            iv1.x = y0 * ww + x0; iv1.y = y0 * ww + x1;
            iv1.z = y1 * ww + x0; iv1.w = y1 * ww + x1;
        }
    }
    float4 a00, a01, a10, a11, b00, b01, b10, b11;
    #define ISSUE(g) { const float4* pg = tagv + ((long)bz * 64 + (g)) * npix; \
        a00 = pg[iv0.x]; a01 = pg[iv0.y]; a10 = pg[iv0.z]; a11 = pg[iv0.w]; \
        if (has1) { b00 = pg[iv1.x]; b01 = pg[iv1.y]; b10 = pg[iv1.z]; b11 = pg[iv1.w]; } }
    #define WRITEBUF(nb) { \
        sbuf[nb][ty0][tx0] = make_float4( \
            a00.x * wv0.x + a01.x * wv0.y + a10.x * wv0.z + a11.x * wv0.w, \
            a00.y * wv0.x + a01.y * wv0.y + a10.y * wv0.z + a11.y * wv0.w, \
            a00.z * wv0.x + a01.z * wv0.y + a10.z * wv0.z + a11.z * wv0.w, \
            a00.w * wv0.x + a01.w * wv0.y + a10.w * wv0.z + a11.w * wv0.w); \
        if (has1) sbuf[nb][ty1][tx1] = make_float4( \
            b00.x * wv1.x + b01.x * wv1.y + b10.x * wv1.z + b11.x * wv1.w, \
            b00.y * wv1.x + b01.y * wv1.y + b10.y * wv1.z + b11.y * wv1.w, \
            b00.z * wv1.x + b01.z * wv1.y + b10.z * wv1.z + b11.z * wv1.w, \
            b00.w * wv1.x + b01.w * wv1.y + b10.w * wv1.z + b11.w * wv1.w); }
    ISSUE(g0);
    WRITEBUF(0);
    __syncthreads();
    int ti = tid >> 4, tj = tid & 15;
    int oi = i0 + ti, oj = j0 + tj;
    long outbase = ((long)bz * 64 + g0) * npix + (long)oi * ww + oj;
    #pragma unroll
    for (int gg = 0; gg < GPB; gg++) {
        const int cur = gg & 1;
        if (gg + 1 < GPB) ISSUE(g0 + gg + 1);
        float4 acc = make_float4(0.f, 0.f, 0.f, 0.f);
        #pragma unroll
        for (int di = 0; di < 3; di++)
            #pragma unroll
            for (int dj = 0; dj < 3; dj++) {
                float4 v = sbuf[cur][ti + di][tj + dj];
                int tap = di * 3 + dj;
                acc.x = fmaf(v.x, dwW[gg][0 * 9 + tap], acc.x);
                acc.y = fmaf(v.y, dwW[gg][1 * 9 + tap], acc.y);
                acc.z = fmaf(v.z, dwW[gg][2 * 9 + tap], acc.z);
                acc.w = fmaf(v.w, dwW[gg][3 * 9 + tap], acc.w);
            }
        float r0 = fmaxf(acc.x, 0.f), r1 = fmaxf(acc.y, 0.f);
        float r2 = fmaxf(acc.z, 0.f), r3 = fmaxf(acc.w, 0.f);
        float4 o;
        o.x = (r0 * pwW[gg][0]  + r1 * pwW[gg][1]  + r2 * pwW[gg][2]  + r3 * pwW[gg][3])  * wscW[gg][0];
        o.y = (r0 * pwW[gg][4]  + r1 * pwW[gg][5]  + r2 * pwW[gg][6]  + r3 * pwW[gg][7])  * wscW[gg][1];
        o.z = (r0 * pwW[gg][8]  + r1 * pwW[gg][9]  + r2 * pwW[gg][10] + r3 * pwW[gg][11]) * wscW[gg][2];
        o.w = (r0 * pwW[gg][12] + r1 * pwW[gg][13] + r2 * pwW[gg][14] + r3 * pwW[gg][15]) * wscW[gg][3];
        outv[outbase + (long)gg * npix] = o;
        if (gg + 1 < GPB) {
            WRITEBUF(cur ^ 1);
            __syncthreads();
        }
    }
    #undef ISSUE
    #undef WRITEBUF
}

// ---------------- k_snake_final: level-0 snake fused with both inverse DWTs + base conv ----------------
__global__ __launch_bounds__(256) void k_snake_final(
    const float4* __restrict__ tagv,          // tag0v
    const float4* __restrict__ tagp1v,
    const float* __restrict__ ox, const float* __restrict__ oy,
    const float* __restrict__ dww, const float* __restrict__ pww,
    const float* __restrict__ wsc,
    const float* __restrict__ x,
    const float* __restrict__ bw, const float* __restrict__ bb,
    const float* __restrict__ bs,
    float* __restrict__ out) {
    const int GPB = 8, hh = 64, ww = 64, npix = 4096;
    __shared__ float4 sbuf[2][18][18];
    __shared__ float xs[2][34][36];
    __shared__ float dwW[GPB][36];
    __shared__ float pwW[GPB][16];
    __shared__ float wscW[GPB][4];
    __shared__ float bwW[GPB][9];
    __shared__ float bbW[GPB];
    __shared__ float bsW[GPB];
    int tile = blockIdx.x;
    int g0 = blockIdx.y * GPB;
    int bz = blockIdx.z;
    int i0 = (tile >> 2) * 16;
    int j0 = (tile & 3) * 16;
    int yy0 = 2 * i0, xx0 = 2 * j0;
    int tid = threadIdx.x;
    for (int t = tid; t < GPB * 36; t += 256) dwW[t / 36][t % 36] = dww[g0 * 36 + t];
    for (int t = tid; t < GPB * 16; t += 256) pwW[t / 16][t % 16] = pww[g0 * 16 + t];
    for (int t = tid; t < GPB * 4;  t += 256) wscW[t / 4][t % 4]  = wsc[g0 * 4 + t];
    for (int t = tid; t < GPB * 9;  t += 256) bwW[t / 9][t % 9]   = bw[g0 * 9 + t];
    if (tid < GPB) { bbW[tid] = bb[g0 + tid]; bsW[tid] = bs[g0 + tid]; }
    const float* oxb = ox + (long)bz * npix;
    const float* oyb = oy + (long)bz * npix;
    float mW = 63.f, mH = 63.f;
    int p0 = tid, p1 = tid + 256;
    bool has1 = (p1 < 324);
    int ty0 = p0 / 18, tx0 = p0 % 18;
    int ty1 = p1 / 18, tx1 = p1 % 18;
    float4 wv0 = make_float4(0.f, 0.f, 0.f, 0.f), wv1 = wv0;
    int4 iv0 = make_int4(0, 0, 0, 0), iv1 = iv0;
    {
        int y = i0 - 1 + ty0, xg = j0 - 1 + tx0;
        if ((unsigned)y < (unsigned)hh && (unsigned)xg < (unsigned)ww) {
            float px = (float)xg + oxb[y * ww + xg];
            float py = (float)y + oyb[y * ww + xg];
            px = reflectf(px, mW); py = reflectf(py, mH);
            float x0f = floorf(px), y0f = floorf(py);
            float fx = px - x0f, fy = py - y0f;
            int x0 = min(max((int)x0f, 0), ww - 1);
            int y0 = min(max((int)y0f, 0), hh - 1);
            int x1 = min(x0 + 1, ww - 1);
            int y1 = min(y0 + 1, hh - 1);
            wv0.x = (1.f - fx) * (1.f - fy); wv0.y = fx * (1.f - fy);
            wv0.z = (1.f - fx) * fy;         wv0.w = fx * fy;
            iv0.x = y0 * ww + x0; iv0.y = y0 * ww + x1;
            iv0.z = y1 * ww + x0; iv0.w = y1 * ww + x1;
        }
        y = i0 - 1 + ty1; xg = j0 - 1 + tx1;
        if (has1 && (unsigned)y < (unsigned)hh && (unsigned)xg < (unsigned)ww) {
            float px = (float)xg + oxb[y * ww + xg];
            float py = (float)y + oyb[y * ww + xg];
            px = reflectf(px, mW); py = reflectf(py, mH);
            float x0f = floorf(px), y0f = floorf(py);
            float fx = px - x0f, fy = py - y0f;
            int x0 = min(max((int)x0f, 0), ww - 1);
            int y0 = min(max((int)y0f, 0), hh - 1);
            int x1 = min(x0 + 1, ww - 1);
            int y1 = min(y0 + 1, hh - 1);
            wv1.x = (1.f - fx) * (1.f - fy); wv1.y = fx * (1.f - fy);
            wv1.z = (1.f - fx) * fy;         wv1.w = fx * fy;
            iv1.x = y0 * ww + x0; iv1.y = y0 * ww + x1;
            iv1.z = y1 * ww + x0; iv1.w = y1 * ww + x1;
        }
    }
    float4 a00, a01, a10, a11, b00, b01, b10, b11;
    #define ISSUE(g) { const float4* pg = tagv + ((long)bz * 64 + (g)) * npix; \
        a00 = pg[iv0.x]; a01 = pg[iv0.y]; a10 = pg[iv0.z]; a11 = pg[iv0.w]; \
        if (has1) { b00 = pg[iv1.x]; b01 = pg[iv1.y]; b10 = pg[iv1.z]; b11 = pg[iv1.w]; } }
    #define WRITEBUF(nb) { \
        sbuf[nb][ty0][tx0] = make_float4( \
            a00.x * wv0.x + a01.x * wv0.y + a10.x * wv0.z + a11.x * wv0.w, \
            a00.y * wv0.x + a01.y * wv0.y + a10.y * wv0.z + a11.y * wv0.w, \
            a00.z * wv0.x + a01.z * wv0.y + a10.z * wv0.z + a11.z * wv0.w, \
            a00.w * wv0.x + a01.w * wv0.y + a10.w * wv0.z + a11.w * wv0.w); \
        if (has1) sbuf[nb][ty1][tx1] = make_float4( \
            b00.x * wv1.x + b01.x * wv1.y + b10.x * wv1.z + b11.x * wv1.w, \
            b00.y * wv1.x + b01.y * wv1.y + b10.y * wv1.z + b11.y * wv1.w, \
            b00.z * wv1.x + b01.z * wv1.y + b10.z * wv1.z + b11.z * wv1.w, \
            b00.w * wv1.x + b01.w * wv1.y + b10.w * wv1.z + b11.w * wv1.w); }
    #define XSTAGE(c, nb) { const float* xbc = x + (long)(bz * 64 + (c)) * 16384; \
        for (int p = tid; p < 34 * 34; p += 256) { \
            int r = p / 34, q = p % 34; \
            int y = yy0 - 1 + r, xg = xx0 - 1 + q; \
            float v = 0.f; \
            if ((unsigned)y < 128u && (unsigned)xg < 128u) v = xbc[y * 128 + xg]; \
            xs[nb][r][q] = v; } }
    ISSUE(g0);
    XSTAGE(g0, 0);
    WRITEBUF(0);
    __syncthreads();
    int ti = tid >> 4, tj = tid & 15;
    int i = i0 + ti, j = j0 + tj;        // half-res coords
    int yy = 2 * i, xx = 2 * j;          // full-res output coords
    float sr = (i & 1) ? -1.f : 1.f;
    float sc = (j & 1) ? -1.f : 1.f;
    long t1base = ((long)(bz * 64)) * 1024 + (long)(i >> 1) * 32 + (j >> 1);
    #pragma unroll
    for (int gg = 0; gg < GPB; gg++) {
        const int cur = gg & 1;
        if (gg + 1 < GPB) ISSUE(g0 + gg + 1);
        float4 d = tagp1v[t1base + (long)(g0 + gg) * 1024];
        if (gg + 1 < GPB) XSTAGE(g0 + gg + 1, cur ^ 1);
        // snake dw conv + relu + pw + scale (identical expressions to R5)
        float4 acc = make_float4(0.f, 0.f, 0.f, 0.f);
        #pragma unroll
        for (int di = 0; di < 3; di++)
            #pragma unroll
            for (int dj = 0; dj < 3; dj++) {
                float4 v = sbuf[cur][ti + di][tj + dj];
                int tap = di * 3 + dj;
                acc.x = fmaf(v.x, dwW[gg][0 * 9 + tap], acc.x);
                acc.y = fmaf(v.y, dwW[gg][1 * 9 + tap], acc.y);
                acc.z = fmaf(v.z, dwW[gg][2 * 9 + tap], acc.z);
                acc.w = fmaf(v.w, dwW[gg][3 * 9 + tap], acc.w);
            }
        float r0 = fmaxf(acc.x, 0.f), r1 = fmaxf(acc.y, 0.f);
        float r2 = fmaxf(acc.z, 0.f), r3 = fmaxf(acc.w, 0.f);
        float4 o;
        o.x = (r0 * pwW[gg][0]  + r1 * pwW[gg][1]  + r2 * pwW[gg][2]  + r3 * pwW[gg][3])  * wscW[gg][0];
        o.y = (r0 * pwW[gg][4]  + r1 * pwW[gg][5]  + r2 * pwW[gg][6]  + r3 * pwW[gg][7])  * wscW[gg][1];
        o.z = (r0 * pwW[gg][8]  + r1 * pwW[gg][9]  + r2 * pwW[gg][10] + r3 * pwW[gg][11]) * wscW[gg][2];
        o.w = (r0 * pwW[gg][12] + r1 * pwW[gg][13] + r2 * pwW[gg][14] + r3 * pwW[gg][15]) * wscW[gg][3];
        // inline level-1 inverse Haar + level-0 inverse Haar (identical expressions to R5 k_final)
        float nv = 0.5f * (d.x + sr * d.y + sc * d.z + sr * sc * d.w);
        float c0 = o.x + nv;
        float c1 = o.y, c2 = o.z, c3 = o.w;
        float rec00 = 0.5f * (c0 + c1 + c2 + c3);
        float rec01 = 0.5f * (c0 + c1 - c2 - c3);
        float rec10 = 0.5f * (c0 - c1 + c2 - c3);
        float rec11 = 0.5f * (c0 - c1 - c2 + c3);
        float bias = bbW[gg], scale = bsW[gg];
        float w0 = bwW[gg][0], w1 = bwW[gg][1], w2 = bwW[gg][2];
        float w3 = bwW[gg][3], w4 = bwW[gg][4], w5 = bwW[gg][5];
        float w6 = bwW[gg][6], w7 = bwW[gg][7], w8 = bwW[gg][8];
        int a = 2 * ti, bq = 2 * tj;
        #define CONV(dy,dx) ({ \
            float accc = bias; \
            accc = fmaf(xs[cur][a+dy+0][bq+dx+0], w0, accc); \
            accc = fmaf(xs[cur][a+dy+0][bq+dx+1], w1, accc); \
            accc = fmaf(xs[cur][a+dy+0][bq+dx+2], w2, accc); \
            accc = fmaf(xs[cur][a+dy+1][bq+dx+0], w3, accc); \
            accc = fmaf(xs[cur][a+dy+1][bq+dx+1], w4, accc); \
            accc = fmaf(xs[cur][a+dy+1][bq+dx+2], w5, accc); \
            accc = fmaf(xs[cur][a+dy+2][bq+dx+0], w6, accc); \
            accc = fmaf(xs[cur][a+dy+2][bq+dx+1], w7, accc); \
            accc = fmaf(xs[cur][a+dy+2][bq+dx+2], w8, accc); \
            accc; })
        float o00 = scale * CONV(0,0) + rec00;
        float o01 = scale * CONV(0,1) + rec01;
        float o10 = scale * CONV(1,0) + rec10;
        float o11 = scale * CONV(1,1) + rec11;
        #undef CONV
        float* ob = out + (((long)(bz * 64 + g0 + gg) * 128) + yy) * 128 + xx;
        *(float2*)ob         = make_float2(o00, o01);
        *(float2*)(ob + 128) = make_float2(o10, o11);
        if (gg + 1 < GPB) {
            WRITEBUF(cur ^ 1);
            __syncthreads();
        }
    }
    #undef ISSUE
    #undef WRITEBUF
    #undef XSTAGE
}

// ---------------- launch ----------------
extern "C" void kernel_launch(void* const* d_in, const int* in_sizes, int n_in,
                              void* d_out, int out_size, void* d_ws, size_t ws_size,
                              hipStream_t stream) {
    const float* x     = (const float*)d_in[0];
    const float* bw    = (const float*)d_in[1];
    const float* bb    = (const float*)d_in[2];
    const float* bs    = (const float*)d_in[3];
    const float* offw0 = (const float*)d_in[4];
    const float* offb0 = (const float*)d_in[5];
    const float* dww0  = (const float*)d_in[6];
    const float* pww0  = (const float*)d_in[7];
    const float* wsc0  = (const float*)d_in[8];
    const float* offw1 = (const float*)d_in[9];
    const float* offb1 = (const float*)d_in[10];
    const float* dww1  = (const float*)d_in[11];
    const float* pww1  = (const float*)d_in[12];
    const float* wsc1  = (const float*)d_in[13];
    float* out = (float*)d_out;
    float* ws = (float*)d_ws;

    float* tag0  = ws + 0L;
    float* tag1  = ws + 16777216L;
    float* tagp1 = ws + 20971520L;
    float* part0 = ws + 25165824L;       // 2*16*65536 floats
    float* avgw  = ws + 41943040L;
    float* avgb  = ws + 41952256L;
    float* ox0   = ws + 41952260L;
    float* oy0   = ws + 42017796L;
    float* ox1   = ws + 42083332L;
    float* oy1   = ws + 42099716L;
    float* part1 = ws + 42116100L;       // 2*16*16384 floats = 524288

    k_prep<<<36, 256, 0, stream>>>(offw0, offb0, offw1, offb1, avgw, avgb);
    k_wt01<<<4096, 256, 0, stream>>>(x, (float4*)tag0, (float4*)tag1);
    // level-1 offsets
    k_off_part<<<dim3(64, 16), 256, 0, stream>>>((const float4*)tag1, avgw, 1, part1, 16, 32, 32);
    k_off_red<<<64, 256, 0, stream>>>(part1, avgb, 1, ox1, oy1, 16384);
    // level-1 snake -> tagp1
    k_snake<4><<<dim3(4, 16, 16), 256, 0, stream>>>((const float4*)tag1, ox1, oy1, dww1, pww1, wsc1,
                                                    (float4*)tagp1, 16, 32, 32);
    // level-0 offsets
    k_off_part<<<dim3(256, 16), 256, 0, stream>>>((const float4*)tag0, avgw, 0, part0, 16, 64, 64);
    k_off_red<<<256, 256, 0, stream>>>(part0, avgb, 0, ox0, oy0, 65536);
    // fused level-0 snake + inverse DWTs + base conv -> out
    k_snake_final<<<dim3(16, 8, 16), 256, 0, stream>>>(
        (const float4*)tag0, (const float4*)tagp1, ox0, oy0, dww0, pww0, wsc0,
        x, bw, bb, bs, out);
}

// Round 7
// 163.272 us; speedup vs baseline: 5.5967x; 1.0883x over previous
//
#include <hip/hip_runtime.h>

typedef _Float16 half4 __attribute__((ext_vector_type(4)));

static __device__ __forceinline__ half4 to_h4(float4 v) {
    half4 h; h.x = (_Float16)v.x; h.y = (_Float16)v.y; h.z = (_Float16)v.z; h.w = (_Float16)v.w; return h;
}
static __device__ __forceinline__ float4 to_f4(half4 h) {
    return make_float4((float)h.x, (float)h.y, (float)h.z, (float)h.w);
}

// ---------------- helpers ----------------
static __device__ __forceinline__ float reflectf(float coord, float m) {
    float period = 2.0f * m;
    float c = fmodf(fabsf(coord), period);
    c = (c > m) ? (period - c) : c;
    return fminf(fmaxf(c, 0.0f), m);
}

// ---------------- k_prep ----------------
__global__ __launch_bounds__(256) void k_prep(
    const float* __restrict__ offw0, const float* __restrict__ offb0,
    const float* __restrict__ offw1, const float* __restrict__ offb1,
    float* __restrict__ avgw, float* __restrict__ avgb) {
    int id = blockIdx.x * blockDim.x + threadIdx.x;
    if (id < 2 * 2 * 2304) {
        int l = id / 4608;
        int rem = id % 4608;
        int d = rem / 2304;
        int r = rem % 2304;
        const float* w = l ? offw1 : offw0;
        float s = w[(d * 3 + 0) * 2304 + r] + w[(d * 3 + 1) * 2304 + r] + w[(d * 3 + 2) * 2304 + r];
        avgw[id] = s * (1.0f / 3.0f);
    }
    if (id == 0) {
        avgb[0] = (offb0[0] + offb0[1] + offb0[2]) * (1.0f / 3.0f);
        avgb[1] = (offb0[3] + offb0[4] + offb0[5]) * (1.0f / 3.0f);
        avgb[2] = (offb1[0] + offb1[1] + offb1[2]) * (1.0f / 3.0f);
        avgb[3] = (offb1[3] + offb1[4] + offb1[5]) * (1.0f / 3.0f);
    }
}

// ---------------- k_wt01: fused level-0 + level-1 Haar DWT (fp16 outputs) ----------------
__global__ __launch_bounds__(256) void k_wt01(
    const float* __restrict__ x, half4* __restrict__ tag0v, half4* __restrict__ tag1v) {
    int id = blockIdx.x * 256 + threadIdx.x;
    if (id >= 16 * 64 * 32 * 32) return;
    int j1 = id & 31; int t = id >> 5;
    int i1 = t & 31; t >>= 5;
    int c = t & 63; int b = t >> 6;
    const float* p = x + ((long)(b * 64 + c) * 128 + 4 * i1) * 128 + 4 * j1;
    float4 r0 = *(const float4*)p;
    float4 r1 = *(const float4*)(p + 128);
    float4 r2 = *(const float4*)(p + 256);
    float4 r3 = *(const float4*)(p + 384);
    #define HAAR(a0,a1,a2,a3) make_float4(0.5f*((a0)+(a1)+(a2)+(a3)), 0.5f*((a0)+(a1)-(a2)-(a3)), \
                                          0.5f*((a0)-(a1)+(a2)-(a3)), 0.5f*((a0)-(a1)-(a2)+(a3)))
    float4 t00 = HAAR(r0.x, r0.y, r1.x, r1.y);
    float4 t01 = HAAR(r0.z, r0.w, r1.z, r1.w);
    float4 t10 = HAAR(r2.x, r2.y, r3.x, r3.y);
    float4 t11 = HAAR(r2.z, r2.w, r3.z, r3.w);
    long pbase = (long)(b * 64 + c) * 4096;
    int i0 = 2 * i1, j0 = 2 * j1;
    tag0v[pbase + (long)i0 * 64 + j0]           = to_h4(t00);
    tag0v[pbase + (long)i0 * 64 + j0 + 1]       = to_h4(t01);
    tag0v[pbase + (long)(i0 + 1) * 64 + j0]     = to_h4(t10);
    tag0v[pbase + (long)(i0 + 1) * 64 + j0 + 1] = to_h4(t11);
    tag1v[(long)(b * 64 + c) * 1024 + (long)i1 * 32 + j1] = to_h4(HAAR(t00.x, t01.x, t10.x, t11.x));
    #undef HAAR
}

// ---------------- k_off_part (fp16 input, fp32 math) ----------------
__global__ __launch_bounds__(256) void k_off_part(
    const half4* __restrict__ tagv, const float* __restrict__ avgw, int level,
    float* __restrict__ part, int B, int hh, int ww) {
    int chunk = blockIdx.y;
    int npix = hh * ww;
    int totpix = B * npix;
    __shared__ float wls[2][4][9][4];
    const float* wsrc = avgw + level * 4608;
    int tid = threadIdx.x;
    if (tid < 288) {
        int d = tid / 144, rem = tid % 144;
        int gg = rem / 36; int tap = (rem % 36) / 4; int cc = tid & 3;
        wls[d][gg][tap][cc] = wsrc[d * 2304 + (chunk * 16 + gg * 4 + cc) * 9 + tap];
    }
    __syncthreads();
    int id = blockIdx.x * 256 + tid;
    if (id >= totpix) return;
    int j = id % ww; int t = id / ww;
    int i = t % hh; int b = t / hh;
    float ax = 0.f, ay = 0.f;
    #pragma unroll
    for (int gg = 0; gg < 4; gg++) {
        const half4* pg = tagv + ((long)b * 64 + chunk * 4 + gg) * npix;
        #pragma unroll
        for (int di = 0; di < 3; di++) {
            int y = i + di - 1;
            if ((unsigned)y >= (unsigned)hh) continue;
            #pragma unroll
            for (int dj = 0; dj < 3; dj++) {
                int x = j + dj - 1;
                if ((unsigned)x >= (unsigned)ww) continue;
                float4 v = to_f4(pg[y * ww + x]);
                const float* wx = &wls[0][gg][di * 3 + dj][0];
                const float* wy = &wls[1][gg][di * 3 + dj][0];
                ax = fmaf(v.x, wx[0], ax); ax = fmaf(v.y, wx[1], ax);
                ax = fmaf(v.z, wx[2], ax); ax = fmaf(v.w, wx[3], ax);
                ay = fmaf(v.x, wy[0], ay); ay = fmaf(v.y, wy[1], ay);
                ay = fmaf(v.z, wy[2], ay); ay = fmaf(v.w, wy[3], ay);
            }
        }
    }
    part[((long)0 * 16 + chunk) * totpix + id] = ax;
    part[((long)1 * 16 + chunk) * totpix + id] = ay;
}

// ---------------- k_off_red ----------------
__global__ __launch_bounds__(256) void k_off_red(
    const float* __restrict__ part, const float* __restrict__ avgb, int level,
    float* __restrict__ ox, float* __restrict__ oy, int totpix) {
    int id = blockIdx.x * 256 + threadIdx.x;
    if (id >= totpix) return;
    float sx = avgb[level * 2 + 0], sy = avgb[level * 2 + 1];
    #pragma unroll
    for (int c = 0; c < 16; c++) sx += part[(long)c * totpix + id];
    #pragma unroll
    for (int c = 0; c < 16; c++) sy += part[((long)16 + c) * totpix + id];
    ox[id] = sx; oy[id] = sy;
}

// ---------------- k_snake (level 1) ----------------
template<int GPB>
__global__ __launch_bounds__(256) void k_snake(
    const half4* __restrict__ tagv,
    const float* __restrict__ ox, const float* __restrict__ oy,
    const float* __restrict__ dww, const float* __restrict__ pww,
    const float* __restrict__ wsc,
    float4* __restrict__ outv, int B, int hh, int ww) {
    __shared__ float4 sbuf[2][18][18];
    __shared__ float dwW[GPB][36];
    __shared__ float pwW[GPB][16];
    __shared__ float wscW[GPB][4];
    int tilesX = ww >> 4;
    int tile = blockIdx.x;
    int g0 = blockIdx.y * GPB;
    int bz = blockIdx.z;
    int i0 = (tile / tilesX) * 16;
    int j0 = (tile % tilesX) * 16;
    int tid = threadIdx.x;
    for (int t = tid; t < GPB * 36; t += 256) dwW[t / 36][t % 36] = dww[g0 * 36 + t];
    for (int t = tid; t < GPB * 16; t += 256) pwW[t / 16][t % 16] = pww[g0 * 16 + t];
    for (int t = tid; t < GPB * 4;  t += 256) wscW[t / 4][t % 4]  = wsc[g0 * 4 + t];
    int npix = hh * ww;
    const float* oxb = ox + (long)bz * npix;
    const float* oyb = oy + (long)bz * npix;
    float mW = (float)(ww - 1), mH = (float)(hh - 1);
    int p0 = tid, p1 = tid + 256;
    bool has1 = (p1 < 324);
    int ty0 = p0 / 18, tx0 = p0 % 18;
    int ty1 = p1 / 18, tx1 = p1 % 18;
    float4 wv0 = make_float4(0.f, 0.f, 0.f, 0.f), wv1 = wv0;
    int4 iv0 = make_int4(0, 0, 0, 0), iv1 = iv0;
    {
        int y = i0 - 1 + ty0, x = j0 - 1 + tx0;
        if (p0 < 324 && (unsigned)y < (unsigned)hh && (unsigned)x < (unsigned)ww) {
            float px = (float)x + oxb[y * ww + x];
            float py = (float)y + oyb[y * ww + x];
            px = reflectf(px, mW); py = reflectf(py, mH);
            float x0f = floorf(px), y0f = floorf(py);
            float fx = px - x0f, fy = py - y0f;
            int x0 = min(max((int)x0f, 0), ww - 1);
            int y0 = min(max((int)y0f, 0), hh - 1);
            int x1 = min(x0 + 1, ww - 1);
            int y1 = min(y0 + 1, hh - 1);
            wv0.x = (1.f - fx) * (1.f - fy); wv0.y = fx * (1.f - fy);
            wv0.z = (1.f - fx) * fy;         wv0.w = fx * fy;
            iv0.x = y0 * ww + x0; iv0.y = y0 * ww + x1;
            iv0.z = y1 * ww + x0; iv0.w = y1 * ww + x1;
        }
        y = i0 - 1 + ty1; x = j0 - 1 + tx1;
        if (has1 && (unsigned)y < (unsigned)hh && (unsigned)x < (unsigned)ww) {
            float px = (float)x + oxb[y * ww + x];
            float py = (float)y + oyb[y * ww + x];
            px = reflectf(px, mW); py = reflectf(py, mH);
            float x0f = floorf(px), y0f = floorf(py);
            float fx = px - x0f, fy = py - y0f;
            int x0 = min(max((int)x0f, 0), ww - 1);
            int y0 = min(max((int)y0f, 0), hh - 1);
            int x1 = min(x0 + 1, ww - 1);
            int y1 = min(y0 + 1, hh - 1);
            wv1.x = (1.f - fx) * (1.f - fy); wv1.y = fx * (1.f - fy);
            wv1.z = (1.f - fx) * fy;         wv1.w = fx * fy;
            iv1.x = y0 * ww + x0; iv1.y = y0 * ww + x1;
            iv1.z = y1 * ww + x0; iv1.w = y1 * ww + x1;
        }
    }
    float4 a00, a01, a10, a11, b00, b01, b10, b11;
    #define ISSUE(g) { const half4* pg = tagv + ((long)bz * 64 + (g)) * npix; \
        a00 = to_f4(pg[iv0.x]); a01 = to_f4(pg[iv0.y]); a10 = to_f4(pg[iv0.z]); a11 = to_f4(pg[iv0.w]); \
        if (has1) { b00 = to_f4(pg[iv1.x]); b01 = to_f4(pg[iv1.y]); b10 = to_f4(pg[iv1.z]); b11 = to_f4(pg[iv1.w]); } }
    #define WRITEBUF(nb) { \
        sbuf[nb][ty0][tx0] = make_float4( \
            a00.x * wv0.x + a01.x * wv0.y + a10.x * wv0.z + a11.x * wv0.w, \
            a00.y * wv0.x + a01.y * wv0.y + a10.y * wv0.z + a11.y * wv0.w, \
            a00.z * wv0.x + a01.z * wv0.y + a10.z * wv0.z + a11.z * wv0.w, \
            a00.w * wv0.x + a01.w * wv0.y + a10.w * wv0.z + a11.w * wv0.w); \
        if (has1) sbuf[nb][ty1][tx1] = make_float4( \
            b00.x * wv1.x + b01.x * wv1.y + b10.x * wv1.z + b11.x * wv1.w, \
            b00.y * wv1.x + b01.y * wv1.y + b10.y * wv1.z + b11.y * wv1.w, \
            b00.z * wv1.x + b01.z * wv1.y + b10.z * wv1.z + b11.z * wv1.w, \
            b00.w * wv1.x + b01.w * wv1.y + b10.w * wv1.z + b11.w * wv1.w); }
    ISSUE(g0);
    WRITEBUF(0);
    __syncthreads();
    int ti = tid >> 4, tj = tid & 15;
    int oi = i0 + ti, oj = j0 + tj;
    long outbase = ((long)bz * 64 + g0) * npix + (long)oi * ww + oj;
    #pragma unroll
    for (int gg = 0; gg < GPB; gg++) {
        const int cur = gg & 1;
        if (gg + 1 < GPB) ISSUE(g0 + gg + 1);
        float4 acc = make_float4(0.f, 0.f, 0.f, 0.f);
        #pragma unroll
        for (int di = 0; di < 3; di++)
            #pragma unroll
            for (int dj = 0; dj < 3; dj++) {
                float4 v = sbuf[cur][ti + di][tj + dj];
                int tap = di * 3 + dj;
                acc.x = fmaf(v.x, dwW[gg][0 * 9 + tap], acc.x);
                acc.y = fmaf(v.y, dwW[gg][1 * 9 + tap], acc.y);
                acc.z = fmaf(v.z, dwW[gg][2 * 9 + tap], acc.z);
                acc.w = fmaf(v.w, dwW[gg][3 * 9 + tap], acc.w);
            }
        float r0 = fmaxf(acc.x, 0.f), r1 = fmaxf(acc.y, 0.f);
        float r2 = fmaxf(acc.z, 0.f), r3 = fmaxf(acc.w, 0.f);
        float4 o;
        o.x = (r0 * pwW[gg][0]  + r1 * pwW[gg][1]  + r2 * pwW[gg][2]  + r3 * pwW[gg][3])  * wscW[gg][0];
        o.y = (r0 * pwW[gg][4]  + r1 * pwW[gg][5]  + r2 * pwW[gg][6]  + r3 * pwW[gg][7])  * wscW[gg][1];
        o.z = (r0 * pwW[gg][8]  + r1 * pwW[gg][9]  + r2 * pwW[gg][10] + r3 * pwW[gg][11]) * wscW[gg][2];
        o.w = (r0 * pwW[gg][12] + r1 * pwW[gg][13] + r2 * pwW[gg][14] + r3 * pwW[gg][15]) * wscW[gg][3];
        outv[outbase + (long)gg * npix] = o;
        if (gg + 1 < GPB) {
            WRITEBUF(cur ^ 1);
            __syncthreads();
        }
    }
    #undef ISSUE
    #undef WRITEBUF
}

// ---------------- k_snake_final: level-0 snake fused with both inverse DWTs + base conv ----------------
__global__ __launch_bounds__(256) void k_snake_final(
    const half4* __restrict__ tagv,           // tag0 fp16
    const float4* __restrict__ tagp1v,
    const float* __restrict__ ox, const float* __restrict__ oy,
    const float* __restrict__ dww, const float* __restrict__ pww,
    const float* __restrict__ wsc,
    const float* __restrict__ x,
    const float* __restrict__ bw, const float* __restrict__ bb,
    const float* __restrict__ bs,
    float* __restrict__ out) {
    const int GPB = 8, hh = 64, ww = 64, npix = 4096;
    __shared__ float4 sbuf[2][18][18];
    __shared__ float xs[2][34][36];
    __shared__ float dwW[GPB][36];
    __shared__ float pwW[GPB][16];
    __shared__ float wscW[GPB][4];
    __shared__ float bwW[GPB][9];
    __shared__ float bbW[GPB];
    __shared__ float bsW[GPB];
    int tile = blockIdx.x;
    int g0 = blockIdx.y * GPB;
    int bz = blockIdx.z;
    int i0 = (tile >> 2) * 16;
    int j0 = (tile & 3) * 16;
    int yy0 = 2 * i0, xx0 = 2 * j0;
    int tid = threadIdx.x;
    for (int t = tid; t < GPB * 36; t += 256) dwW[t / 36][t % 36] = dww[g0 * 36 + t];
    for (int t = tid; t < GPB * 16; t += 256) pwW[t / 16][t % 16] = pww[g0 * 16 + t];
    for (int t = tid; t < GPB * 4;  t += 256) wscW[t / 4][t % 4]  = wsc[g0 * 4 + t];
    for (int t = tid; t < GPB * 9;  t += 256) bwW[t / 9][t % 9]   = bw[g0 * 9 + t];
    if (tid < GPB) { bbW[tid] = bb[g0 + tid]; bsW[tid] = bs[g0 + tid]; }
    const float* oxb = ox + (long)bz * npix;
    const float* oyb = oy + (long)bz * npix;
    float mW = 63.f, mH = 63.f;
    int p0 = tid, p1 = tid + 256;
    bool has1 = (p1 < 324);
    int ty0 = p0 / 18, tx0 = p0 % 18;
    int ty1 = p1 / 18, tx1 = p1 % 18;
    float4 wv0 = make_float4(0.f, 0.f, 0.f, 0.f), wv1 = wv0;
    int4 iv0 = make_int4(0, 0, 0, 0), iv1 = iv0;
    {
        int y = i0 - 1 + ty0, xg = j0 - 1 + tx0;
        if ((unsigned)y < (unsigned)hh && (unsigned)xg < (unsigned)ww) {
            float px = (float)xg + oxb[y * ww + xg];
            float py = (float)y + oyb[y * ww + xg];
            px = reflectf(px, mW); py = reflectf(py, mH);
            float x0f = floorf(px), y0f = floorf(py);
            float fx = px - x0f, fy = py - y0f;
            int x0 = min(max((int)x0f, 0), ww - 1);
            int y0 = min(max((int)y0f, 0), hh - 1);
            int x1 = min(x0 + 1, ww - 1);
            int y1 = min(y0 + 1, hh - 1);
            wv0.x = (1.f - fx) * (1.f - fy); wv0.y = fx * (1.f - fy);
            wv0.z = (1.f - fx) * fy;         wv0.w = fx * fy;
            iv0.x = y0 * ww + x0; iv0.y = y0 * ww + x1;
            iv0.z = y1 * ww + x0; iv0.w = y1 * ww + x1;
        }
        y = i0 - 1 + ty1; xg = j0 - 1 + tx1;
        if (has1 && (unsigned)y < (unsigned)hh && (unsigned)xg < (unsigned)ww) {
            float px = (float)xg + oxb[y * ww + xg];
            float py = (float)y + oyb[y * ww + xg];
            px = reflectf(px, mW); py = reflectf(py, mH);
            float x0f = floorf(px), y0f = floorf(py);
            float fx = px - x0f, fy = py - y0f;
            int x0 = min(max((int)x0f, 0), ww - 1);
            int y0 = min(max((int)y0f, 0), hh - 1);
            int x1 = min(x0 + 1, ww - 1);
            int y1 = min(y0 + 1, hh - 1);
            wv1.x = (1.f - fx) * (1.f - fy); wv1.y = fx * (1.f - fy);
            wv1.z = (1.f - fx) * fy;         wv1.w = fx * fy;
            iv1.x = y0 * ww + x0; iv1.y = y0 * ww + x1;
            iv1.z = y1 * ww + x0; iv1.w = y1 * ww + x1;
        }
    }
    float4 a00, a01, a10, a11, b00, b01, b10, b11;
    #define ISSUE(g) { const half4* pg = tagv + ((long)bz * 64 + (g)) * npix; \
        a00 = to_f4(pg[iv0.x]); a01 = to_f4(pg[iv0.y]); a10 = to_f4(pg[iv0.z]); a11 = to_f4(pg[iv0.w]); \
        if (has1) { b00 = to_f4(pg[iv1.x]); b01 = to_f4(pg[iv1.y]); b10 = to_f4(pg[iv1.z]); b11 = to_f4(pg[iv1.w]); } }
    #define WRITEBUF(nb) { \
        sbuf[nb][ty0][tx0] = make_float4( \
            a00.x * wv0.x + a01.x * wv0.y + a10.x * wv0.z + a11.x * wv0.w, \
            a00.y * wv0.x + a01.y * wv0.y + a10.y * wv0.z + a11.y * wv0.w, \
            a00.z * wv0.x + a01.z * wv0.y + a10.z * wv0.z + a11.z * wv0.w, \
            a00.w * wv0.x + a01.w * wv0.y + a10.w * wv0.z + a11.w * wv0.w); \
        if (has1) sbuf[nb][ty1][tx1] = make_float4( \
            b00.x * wv1.x + b01.x * wv1.y + b10.x * wv1.z + b11.x * wv1.w, \
            b00.y * wv1.x + b01.y * wv1.y + b10.y * wv1.z + b11.y * wv1.w, \
            b00.z * wv1.x + b01.z * wv1.y + b10.z * wv1.z + b11.z * wv1.w, \
            b00.w * wv1.x + b01.w * wv1.y + b10.w * wv1.z + b11.w * wv1.w); }
    #define XSTAGE(c, nb) { const float* xbc = x + (long)(bz * 64 + (c)) * 16384; \
        for (int p = tid; p < 34 * 34; p += 256) { \
            int r = p / 34, q = p % 34; \
            int y = yy0 - 1 + r, xg = xx0 - 1 + q; \
            float v = 0.f; \
            if ((unsigned)y < 128u && (unsigned)xg < 128u) v = xbc[y * 128 + xg]; \
            xs[nb][r][q] = v; } }
    ISSUE(g0);
    XSTAGE(g0, 0);
    WRITEBUF(0);
    __syncthreads();
    int ti = tid >> 4, tj = tid & 15;
    int i = i0 + ti, j = j0 + tj;
    int yy = 2 * i, xx = 2 * j;
    float sr = (i & 1) ? -1.f : 1.f;
    float sc = (j & 1) ? -1.f : 1.f;
    long t1base = ((long)(bz * 64)) * 1024 + (long)(i >> 1) * 32 + (j >> 1);
    #pragma unroll
    for (int gg = 0; gg < GPB; gg++) {
        const int cur = gg & 1;
        if (gg + 1 < GPB) ISSUE(g0 + gg + 1);
        float4 d = tagp1v[t1base + (long)(g0 + gg) * 1024];
        if (gg + 1 < GPB) XSTAGE(g0 + gg + 1, cur ^ 1);
        float4 acc = make_float4(0.f, 0.f, 0.f, 0.f);
        #pragma unroll
        for (int di = 0; di < 3; di++)
            #pragma unroll
            for (int dj = 0; dj < 3; dj++) {
                float4 v = sbuf[cur][ti + di][tj + dj];
                int tap = di * 3 + dj;
                acc.x = fmaf(v.x, dwW[gg][0 * 9 + tap], acc.x);
                acc.y = fmaf(v.y, dwW[gg][1 * 9 + tap], acc.y);
                acc.z = fmaf(v.z, dwW[gg][2 * 9 + tap], acc.z);
                acc.w = fmaf(v.w, dwW[gg][3 * 9 + tap], acc.w);
            }
        float r0 = fmaxf(acc.x, 0.f), r1 = fmaxf(acc.y, 0.f);
        float r2 = fmaxf(acc.z, 0.f), r3 = fmaxf(acc.w, 0.f);
        float4 o;
        o.x = (r0 * pwW[gg][0]  + r1 * pwW[gg][1]  + r2 * pwW[gg][2]  + r3 * pwW[gg][3])  * wscW[gg][0];
        o.y = (r0 * pwW[gg][4]  + r1 * pwW[gg][5]  + r2 * pwW[gg][6]  + r3 * pwW[gg][7])  * wscW[gg][1];
        o.z = (r0 * pwW[gg][8]  + r1 * pwW[gg][9]  + r2 * pwW[gg][10] + r3 * pwW[gg][11]) * wscW[gg][2];
        o.w = (r0 * pwW[gg][12] + r1 * pwW[gg][13] + r2 * pwW[gg][14] + r3 * pwW[gg][15]) * wscW[gg][3];
        float nv = 0.5f * (d.x + sr * d.y + sc * d.z + sr * sc * d.w);
        float c0 = o.x + nv;
        float c1 = o.y, c2 = o.z, c3 = o.w;
        float rec00 = 0.5f * (c0 + c1 + c2 + c3);
        float rec01 = 0.5f * (c0 + c1 - c2 - c3);
        float rec10 = 0.5f * (c0 - c1 + c2 - c3);
        float rec11 = 0.5f * (c0 - c1 - c2 + c3);
        float bias = bbW[gg], scale = bsW[gg];
        float w0 = bwW[gg][0], w1 = bwW[gg][1], w2 = bwW[gg][2];
        float w3 = bwW[gg][3], w4 = bwW[gg][4], w5 = bwW[gg][5];
        float w6 = bwW[gg][6], w7 = bwW[gg][7], w8 = bwW[gg][8];
        int a = 2 * ti, bq = 2 * tj;
        #define CONV(dy,dx) ({ \
            float accc = bias; \
            accc = fmaf(xs[cur][a+dy+0][bq+dx+0], w0, accc); \
            accc = fmaf(xs[cur][a+dy+0][bq+dx+1], w1, accc); \
            accc = fmaf(xs[cur][a+dy+0][bq+dx+2], w2, accc); \
            accc = fmaf(xs[cur][a+dy+1][bq+dx+0], w3, accc); \
            accc = fmaf(xs[cur][a+dy+1][bq+dx+1], w4, accc); \
            accc = fmaf(xs[cur][a+dy+1][bq+dx+2], w5, accc); \
            accc = fmaf(xs[cur][a+dy+2][bq+dx+0], w6, accc); \
            accc = fmaf(xs[cur][a+dy+2][bq+dx+1], w7, accc); \
            accc = fmaf(xs[cur][a+dy+2][bq+dx+2], w8, accc); \
            accc; })
        float o00 = scale * CONV(0,0) + rec00;
        float o01 = scale * CONV(0,1) + rec01;
        float o10 = scale * CONV(1,0) + rec10;
        float o11 = scale * CONV(1,1) + rec11;
        #undef CONV
        float* ob = out + (((long)(bz * 64 + g0 + gg) * 128) + yy) * 128 + xx;
        *(float2*)ob         = make_float2(o00, o01);
        *(float2*)(ob + 128) = make_float2(o10, o11);
        if (gg + 1 < GPB) {
            WRITEBUF(cur ^ 1);
            __syncthreads();
        }
    }
    #undef ISSUE
    #undef WRITEBUF
    #undef XSTAGE
}

// ---------------- launch ----------------
extern "C" void kernel_launch(void* const* d_in, const int* in_sizes, int n_in,
                              void* d_out, int out_size, void* d_ws, size_t ws_size,
                              hipStream_t stream) {
    const float* x     = (const float*)d_in[0];
    const float* bw    = (const float*)d_in[1];
    const float* bb    = (const float*)d_in[2];
    const float* bs    = (const float*)d_in[3];
    const float* offw0 = (const float*)d_in[4];
    const float* offb0 = (const float*)d_in[5];
    const float* dww0  = (const float*)d_in[6];
    const float* pww0  = (const float*)d_in[7];
    const float* wsc0  = (const float*)d_in[8];
    const float* offw1 = (const float*)d_in[9];
    const float* offb1 = (const float*)d_in[10];
    const float* dww1  = (const float*)d_in[11];
    const float* pww1  = (const float*)d_in[12];
    const float* wsc1  = (const float*)d_in[13];
    float* out = (float*)d_out;
    float* ws = (float*)d_ws;

    // workspace layout (float offsets)
    half4* tag0h = (half4*)(ws + 0L);            // 4,194,304 half4 = 33.5 MB = 8,388,608 floats
    half4* tag1h = (half4*)(ws + 8388608L);      // 1,048,576 half4 = 8.4 MB = 2,097,152 floats
    float* tagp1 = ws + 10485760L;               // 4,194,304 floats (float4 x 1,048,576)
    float* part0 = ws + 14680064L;               // 2,097,152 floats
    float* part1 = ws + 16777216L;               //   524,288 floats
    float* avgw  = ws + 17301504L;               //     9,216
    float* avgb  = ws + 17310720L;               //         4
    float* ox0   = ws + 17310724L;               //    65,536
    float* oy0   = ws + 17376260L;               //    65,536
    float* ox1   = ws + 17441796L;               //    16,384
    float* oy1   = ws + 17458180L;               //    16,384

    k_prep<<<36, 256, 0, stream>>>(offw0, offb0, offw1, offb1, avgw, avgb);
    k_wt01<<<4096, 256, 0, stream>>>(x, tag0h, tag1h);
    // level-1 offsets
    k_off_part<<<dim3(64, 16), 256, 0, stream>>>(tag1h, avgw, 1, part1, 16, 32, 32);
    k_off_red<<<64, 256, 0, stream>>>(part1, avgb, 1, ox1, oy1, 16384);
    // level-1 snake -> tagp1
    k_snake<4><<<dim3(4, 16, 16), 256, 0, stream>>>(tag1h, ox1, oy1, dww1, pww1, wsc1,
                                                    (float4*)tagp1, 16, 32, 32);
    // level-0 offsets
    k_off_part<<<dim3(256, 16), 256, 0, stream>>>(tag0h, avgw, 0, part0, 16, 64, 64);
    k_off_red<<<256, 256, 0, stream>>>(part0, avgb, 0, ox0, oy0, 65536);
    // fused level-0 snake + inverse DWTs + base conv -> out
    k_snake_final<<<dim3(16, 8, 16), 256, 0, stream>>>(
        tag0h, (const float4*)tagp1, ox0, oy0, dww0, pww0, wsc0,
        x, bw, bb, bs, out);
}